// Round 7
// baseline (273.005 us; speedup 1.0000x reference)
//
#include <hip/hip_runtime.h>
#include <stdint.h>

typedef unsigned short u16;
typedef __attribute__((ext_vector_type(8))) short bf16x8;
typedef __attribute__((ext_vector_type(4))) float f32x4;

#define LN_THETA 9.210340371976184f
#define SLEN 4096
#define DMODEL 1024

__device__ __forceinline__ u16 f2bf(float f) {
  union { float f; unsigned u; } v; v.f = f;
  unsigned u = v.u;
  return (u16)((u + 0x7FFFu + ((u >> 16) & 1u)) >> 16);
}
__device__ __forceinline__ u16 f2bf_trunc(float f) {
  union { float f; unsigned u; } v; v.f = f;
  return (u16)(v.u >> 16);
}

__device__ __forceinline__ f32x4 mfma16(bf16x8 a, bf16x8 b, f32x4 c) {
  return __builtin_amdgcn_mfma_f32_16x16x32_bf16(a, b, c, 0, 0, 0);
}

__device__ __forceinline__ void async16(const u16* g, u16* l) {
  __builtin_amdgcn_global_load_lds(
      (const __attribute__((address_space(1))) unsigned int*)g,
      (__attribute__((address_space(3))) unsigned int*)l, 16, 0, 0);
}

// ---- RoPE table: tab[s*32+i] = (cos, sin)(pos[s] * theta^(-2i/64))
__global__ void rope_tab_kernel(const int* __restrict__ tokpos,
                                float2* __restrict__ tab) {
  int t = blockIdx.x * 256 + threadIdx.x;   // 0 .. 4096*32-1
  int s = t >> 5, i = t & 31;
  float inv = expf(-(float)(2 * i) * (LN_THETA / 64.0f));
  float ang = (float)tokpos[s] * inv;
  float sn, cs;
  sincosf(ang, &sn, &cs);
  tab[t] = make_float2(cs, sn);
}

// ---- fp32 -> bf16 (RNE), 4 elems/thread
__global__ void cvt_kernel(const float* __restrict__ src, u16* __restrict__ dst,
                           int n4) {
  int i = blockIdx.x * 256 + threadIdx.x;
  if (i >= n4) return;
  float4 v = ((const float4*)src)[i];
  ushort4 o;
  o.x = f2bf(v.x); o.y = f2bf(v.y); o.z = f2bf(v.z); o.w = f2bf(v.w);
  ((ushort4*)dst)[i] = o;
}

// ---- 128x128 bf16 MFMA GEMM, qkv^T: D = Wqkv(3072xK) . x(4096xK)^T
// Fused RoPE; outputs routed through an LDS transpose so ALL global
// writes are contiguous 128B rows (old epilogue scattered u16 at 8KB
// stride for vT -> one 64B line per 2B store).
__global__ __launch_bounds__(256) void gemm_qkv_kernel(
    const u16* __restrict__ A, const u16* __restrict__ B,
    u16* __restrict__ qb, u16* __restrict__ kb,
    u16* __restrict__ vbT, const float2* __restrict__ cstab) {
  const int K = 1024;
  __shared__ __align__(16) u16 As[128][32];
  __shared__ __align__(16) u16 Bs[128][32];
  __shared__ __align__(16) u16 Ts[128][136];   // transpose scratch (+8 pad)
  const int tid = threadIdx.x;
  const int wave = tid >> 6, lane = tid & 63;
  const int quad = lane >> 4, col = lane & 15;
  const int rowBase = blockIdx.x * 128;
  const int colBase = blockIdx.y * 128;
  const int wm = (wave >> 1) * 64, wn = (wave & 1) * 64;

  const int sRow = wave * 32 + (lane >> 2);
  const int sK = (lane & 3) * 8;
  const u16* gA = A + (size_t)(rowBase + sRow) * K + sK;
  const u16* gB = B + (size_t)(colBase + sRow) * K + sK;

  f32x4 acc[4][4];
#pragma unroll
  for (int i = 0; i < 4; ++i)
#pragma unroll
    for (int j = 0; j < 4; ++j)
      acc[i][j] = f32x4{0.f, 0.f, 0.f, 0.f};

  for (int kk = 0; kk < K; kk += 32) {
    __syncthreads();
    async16(gA + kk, &As[sRow][sK]);
    async16(gA + kk + 16 * K, &As[sRow + 16][sK]);
    async16(gB + kk, &Bs[sRow][sK]);
    async16(gB + kk + 16 * K, &Bs[sRow + 16][sK]);
    __syncthreads();
    bf16x8 af[4], bfr[4];
#pragma unroll
    for (int i = 0; i < 4; ++i)
      af[i] = *(const bf16x8*)&As[wm + i * 16 + col][quad * 8];
#pragma unroll
    for (int j = 0; j < 4; ++j)
      bfr[j] = *(const bf16x8*)&Bs[wn + j * 16 + col][quad * 8];
#pragma unroll
    for (int i = 0; i < 4; ++i)
#pragma unroll
      for (int j = 0; j < 4; ++j)
        acc[i][j] = mfma16(af[i], bfr[j], acc[i][j]);
  }

  const int sec = rowBase >> 10;   // block-uniform: 0=q 1=k 2=v

  if (sec < 2) {
    // RoPE in registers, write TRANSPOSED tile Ts[s_local][e_local]
#pragma unroll
    for (int j = 0; j < 4; ++j) {
      int sl = wn + j * 16 + col;
      int s = colBase + sl;
#pragma unroll
      for (int i = 0; i < 4; ++i) {
        int el = wm + i * 16 + quad * 4;
        int d = (rowBase + el) & 63;           // d % 4 == 0
        float v0 = acc[i][j][0], v1 = acc[i][j][1];
        float v2 = acc[i][j][2], v3 = acc[i][j][3];
        float2 cs0 = cstab[s * 32 + (d >> 1)];
        float2 cs1 = cstab[s * 32 + (d >> 1) + 1];
        ushort4 pk;
        pk.x = f2bf(v0 * cs0.x - v1 * cs0.y);
        pk.y = f2bf(v1 * cs0.x + v0 * cs0.y);
        pk.z = f2bf(v2 * cs1.x - v3 * cs1.y);
        pk.w = f2bf(v3 * cs1.x + v2 * cs1.y);
        *(ushort4*)&Ts[sl][el] = pk;           // 8B aligned
      }
    }
    __syncthreads();
    // coalesced store: thread = (s row, head half); 128B contiguous
    int sl = tid >> 1, hf = tid & 1;
    int hh = ((rowBase & 1023) >> 6) + hf;
    u16* dst = (sec == 0 ? qb : kb) + ((size_t)hh * SLEN + colBase + sl) * 64;
    const u16* srcp = &Ts[sl][hf * 64];
#pragma unroll
    for (int kq = 0; kq < 8; ++kq)
      ((int4*)dst)[kq] = ((const int4*)srcp)[kq];
  } else {
    // v: C-layout is already v^T[d][s]; write direct Ts[e_local][s_local]
#pragma unroll
    for (int j = 0; j < 4; ++j) {
      int sl = wn + j * 16 + col;
#pragma unroll
      for (int i = 0; i < 4; ++i) {
        int el = wm + i * 16 + quad * 4;
#pragma unroll
        for (int r = 0; r < 4; ++r)
          Ts[el + r][sl] = f2bf(acc[i][j][r]);
      }
    }
    __syncthreads();
    int el = tid >> 1, sh = tid & 1;
    int e = rowBase - 2048 + el;
    int hh = e >> 6, d = e & 63;
    u16* dst = vbT + (size_t)(hh * 64 + d) * SLEN + colBase + sh * 64;
    const u16* srcp = &Ts[el][sh * 64];
#pragma unroll
    for (int kq = 0; kq < 8; ++kq)
      ((int4*)dst)[kq] = ((const int4*)srcp)[kq];
  }
}

// ---- 128x64 bf16 MFMA GEMM, out = attn(4096xK) . Wo(1024xK)^T, fp32 out.
__global__ __launch_bounds__(256) void gemm_out_kernel(
    const u16* __restrict__ A, const u16* __restrict__ B,
    float* __restrict__ outf) {
  const int K = 1024;
  __shared__ __align__(16) u16 As[128][32];
  __shared__ __align__(16) u16 Bs[64][32];
  const int tid = threadIdx.x;
  const int wave = tid >> 6, lane = tid & 63;
  const int quad = lane >> 4, col = lane & 15;
  const int rowBase = blockIdx.x * 128;
  const int colBase = blockIdx.y * 64;

  const int sRow = wave * 32 + (lane >> 2);
  const int bRow = wave * 16 + (lane >> 2);
  const int sK = (lane & 3) * 8;
  const u16* gA = A + (size_t)(rowBase + sRow) * K + sK;
  const u16* gB = B + (size_t)(colBase + bRow) * K + sK;

  f32x4 acc[2][4];
#pragma unroll
  for (int i = 0; i < 2; ++i)
#pragma unroll
    for (int j = 0; j < 4; ++j)
      acc[i][j] = f32x4{0.f, 0.f, 0.f, 0.f};

  for (int kk = 0; kk < K; kk += 32) {
    __syncthreads();
    async16(gA + kk, &As[sRow][sK]);
    async16(gA + kk + 16 * K, &As[sRow + 16][sK]);
    async16(gB + kk, &Bs[bRow][sK]);
    __syncthreads();
    bf16x8 af[2], bfr[4];
#pragma unroll
    for (int i = 0; i < 2; ++i)
      af[i] = *(const bf16x8*)&As[wave * 32 + i * 16 + col][quad * 8];
#pragma unroll
    for (int j = 0; j < 4; ++j)
      bfr[j] = *(const bf16x8*)&Bs[j * 16 + col][quad * 8];
#pragma unroll
    for (int i = 0; i < 2; ++i)
#pragma unroll
      for (int j = 0; j < 4; ++j)
        acc[i][j] = mfma16(af[i], bfr[j], acc[i][j]);
  }

#pragma unroll
  for (int i = 0; i < 2; ++i) {
    int r0 = rowBase + wave * 32 + i * 16 + quad * 4;
#pragma unroll
    for (int j = 0; j < 4; ++j) {
      int cc = colBase + j * 16 + col;
#pragma unroll
      for (int r = 0; r < 4; ++r)
        outf[(size_t)(r0 + r) * DMODEL + cc] = acc[i][j][r];
    }
  }
}

// ---- causal flash attention v7: 128-row q-tiles, 4 waves/block.
// One staged K/V chunk feeds 4 waves (staging insts per unit work halved).
// Grid (16 heads, 32): tile = y<16 ? 31-y : y-16, so the two blocks
// co-resident on a CU (y, y+16 in round-robin dispatch) sum to 66 chunks.
// Pld per-wave per-strip (strip-shared variant raced under graph replay).
__global__ __launch_bounds__(256) void flash_kernel(
    const u16* __restrict__ qbuf, const u16* __restrict__ kbuf,
    const u16* __restrict__ vbT, u16* __restrict__ attn) {
  const int S = SLEN;
  const int h = blockIdx.x;
  const int yy = blockIdx.y;
  const int tile = (yy < 16) ? (31 - yy) : (yy - 16);
  const int wave = threadIdx.x >> 6, lane = threadIdx.x & 63;
  const int quad = lane >> 4, col = lane & 15;
  const u16* Q = qbuf + (size_t)h * S * 64;
  const u16* Kh = kbuf + (size_t)h * S * 64;
  const u16* Vt = vbT + (size_t)h * 64 * S;

  __shared__ __align__(16) u16 Ks[2][64][64];
  __shared__ __align__(16) u16 Vs[2][64][64];
  __shared__ __align__(16) u16 Pld[4][2][16][72];  // [wave][strip]

  const int sr = lane >> 3;                    // 0..7
  const int sw = ((lane & 7) ^ sr) * 8;        // swizzled global seg
  const int dcol = (lane & 7) * 8;             // LDS seg = lane order
  const int segA = ((quad ^ (col & 7)) * 8);
  const int segB = (((quad ^ 4) ^ (col & 7)) * 8);

  const int nch = 2 * tile + 2;
  const int qrow0 = tile * 128 + wave * 32;

  bf16x8 qf0[2], qf1[2];
#pragma unroll
  for (int i = 0; i < 2; ++i) {
    const u16* qp = &Q[(size_t)(qrow0 + i * 16 + col) * 64 + quad * 8];
    qf0[i] = *(const bf16x8*)qp;
    qf1[i] = *(const bf16x8*)(qp + 32);
  }

  f32x4 o[2][4];
#pragma unroll
  for (int i = 0; i < 2; ++i)
#pragma unroll
    for (int n = 0; n < 4; ++n) o[i][n] = f32x4{0.f, 0.f, 0.f, 0.f};
  float lrow[2][4] = {{0.f, 0.f, 0.f, 0.f}, {0.f, 0.f, 0.f, 0.f}};

  auto stage = [&](int c, int b) {
    const int k0 = c * 64;
#pragma unroll
    for (int t = 0; t < 2; ++t) {
      int row = (t * 4 + wave) * 8 + sr;
      async16(Kh + (size_t)(k0 + row) * 64 + sw, &Ks[b][row][dcol]);
      async16(Vt + (size_t)row * S + k0 + sw, &Vs[b][row][dcol]);
    }
  };

  stage(0, 0);

  for (int c = 0; c < nch; ++c) {
    const int b = c & 1;
    const int k0 = c * 64;
    __syncthreads();        // drains async stage of chunk c
    if (c + 1 < nch) stage(c + 1, b ^ 1);

    bf16x8 kf0[4], kf1[4], vf0[4], vf1[4];
#pragma unroll
    for (int j = 0; j < 4; ++j) {
      kf0[j] = *(const bf16x8*)&Ks[b][16 * j + col][segA];
      kf1[j] = *(const bf16x8*)&Ks[b][16 * j + col][segB];
    }
#pragma unroll
    for (int n = 0; n < 4; ++n) {
      vf0[n] = *(const bf16x8*)&Vs[b][16 * n + col][segA];
      vf1[n] = *(const bf16x8*)&Vs[b][16 * n + col][segB];
    }
#pragma unroll
    for (int i = 0; i < 2; ++i) {
      const int qs0 = qrow0 + i * 16;       // strip's first q row
      if (k0 > qs0 + 15) continue;          // strip fully masked (uniform)
      const bool needmask = (k0 + 63 > qs0);
      f32x4 s[4];
#pragma unroll
      for (int j = 0; j < 4; ++j)
        s[j] = mfma16(qf1[i], kf1[j],
                      mfma16(qf0[i], kf0[j], f32x4{0.f, 0.f, 0.f, 0.f}));
      float p[4][4];
#pragma unroll
      for (int r = 0; r < 4; ++r) {
        const int qabs = qs0 + quad * 4 + r;
#pragma unroll
        for (int j = 0; j < 4; ++j) {
          float e = __expf(s[j][r] * 0.125f);
          if (needmask && (k0 + 16 * j + col > qabs)) e = 0.f;
          p[j][r] = e;
        }
        lrow[i][r] += (p[0][r] + p[1][r]) + (p[2][r] + p[3][r]);
      }
#pragma unroll
      for (int j = 0; j < 4; ++j)
#pragma unroll
        for (int r = 0; r < 4; ++r)
          Pld[wave][i][quad * 4 + r][16 * j + col] = f2bf_trunc(p[j][r]);
      bf16x8 pa0 = *(const bf16x8*)&Pld[wave][i][col][quad * 8];
      bf16x8 pa1 = *(const bf16x8*)&Pld[wave][i][col][quad * 8 + 32];
#pragma unroll
      for (int n = 0; n < 4; ++n)
        o[i][n] = mfma16(pa1, vf1[n], mfma16(pa0, vf0[n], o[i][n]));
    }
  }

#pragma unroll
  for (int i = 0; i < 2; ++i) {
#pragma unroll
    for (int m = 1; m <= 8; m <<= 1)
#pragma unroll
      for (int r = 0; r < 4; ++r) lrow[i][r] += __shfl_xor(lrow[i][r], m);
#pragma unroll
    for (int r = 0; r < 4; ++r) {
      float inv = 1.0f / lrow[i][r];
      int row = qrow0 + i * 16 + quad * 4 + r;
      u16* dst = &attn[(size_t)row * DMODEL + h * 64 + col];
#pragma unroll
      for (int n = 0; n < 4; ++n) dst[16 * n] = f2bf(o[i][n][r] * inv);
    }
  }
}

extern "C" void kernel_launch(void* const* d_in, const int* in_sizes, int n_in,
                              void* d_out, int out_size, void* d_ws,
                              size_t ws_size, hipStream_t stream) {
  const float* x = (const float*)d_in[0];
  const int* tokpos = (const int*)d_in[1];
  const float* wqkv = (const float*)d_in[2];
  const float* wo = (const float*)d_in[3];
  float* out = (float*)d_out;

  char* ws = (char*)d_ws;
  u16* xb    = (u16*)(ws);
  u16* wqkvb = (u16*)(ws + ((size_t)8 << 20));
  u16* wob   = (u16*)(ws + ((size_t)14 << 20));
  u16* qb    = (u16*)(ws + ((size_t)16 << 20));
  u16* kb    = (u16*)(ws + ((size_t)24 << 20));
  u16* vbT   = (u16*)(ws + ((size_t)32 << 20));
  u16* attn  = (u16*)(ws + ((size_t)40 << 20));
  float2* cstab = (float2*)(ws + ((size_t)48 << 20));

  rope_tab_kernel<<<dim3(512), dim3(256), 0, stream>>>(tokpos, cstab);
  cvt_kernel<<<dim3(4096), dim3(256), 0, stream>>>(x, xb, 1 << 20);
  cvt_kernel<<<dim3(3072), dim3(256), 0, stream>>>(wqkv, wqkvb, 3 << 18);
  cvt_kernel<<<dim3(1024), dim3(256), 0, stream>>>(wo, wob, 1 << 18);
  gemm_qkv_kernel<<<dim3(24, 32), dim3(256), 0, stream>>>(
      wqkvb, xb, qb, kb, vbT, cstab);
  flash_kernel<<<dim3(16, 32), dim3(256), 0, stream>>>(qb, kb, vbT, attn);
  gemm_out_kernel<<<dim3(32, 16), dim3(256), 0, stream>>>(attn, wob, out);
}

// Round 8
// 246.381 us; speedup vs baseline: 1.1081x; 1.1081x over previous
//
#include <hip/hip_runtime.h>
#include <stdint.h>

typedef unsigned short u16;
typedef __attribute__((ext_vector_type(8))) short bf16x8;
typedef __attribute__((ext_vector_type(4))) float f32x4;

#define LN_THETA 9.210340371976184f
#define SLEN 4096
#define DMODEL 1024

__device__ __forceinline__ u16 f2bf(float f) {
  union { float f; unsigned u; } v; v.f = f;
  unsigned u = v.u;
  return (u16)((u + 0x7FFFu + ((u >> 16) & 1u)) >> 16);
}
__device__ __forceinline__ u16 f2bf_trunc(float f) {
  union { float f; unsigned u; } v; v.f = f;
  return (u16)(v.u >> 16);
}

__device__ __forceinline__ f32x4 mfma16(bf16x8 a, bf16x8 b, f32x4 c) {
  return __builtin_amdgcn_mfma_f32_16x16x32_bf16(a, b, c, 0, 0, 0);
}

__device__ __forceinline__ void async16(const u16* g, u16* l) {
  __builtin_amdgcn_global_load_lds(
      (const __attribute__((address_space(1))) unsigned int*)g,
      (__attribute__((address_space(3))) unsigned int*)l, 16, 0, 0);
}

// ---- RoPE table: tab[s*32+i] = (cos, sin)(pos[s] * theta^(-2i/64))
__global__ void rope_tab_kernel(const int* __restrict__ tokpos,
                                float2* __restrict__ tab) {
  int t = blockIdx.x * 256 + threadIdx.x;   // 0 .. 4096*32-1
  int s = t >> 5, i = t & 31;
  float inv = expf(-(float)(2 * i) * (LN_THETA / 64.0f));
  float ang = (float)tokpos[s] * inv;
  float sn, cs;
  sincosf(ang, &sn, &cs);
  tab[t] = make_float2(cs, sn);
}

// ---- fp32 -> bf16 (RNE), all three inputs in one launch
__global__ void cvt_all_kernel(const float* __restrict__ x,
                               const float* __restrict__ wqkv,
                               const float* __restrict__ wo,
                               u16* __restrict__ xb, u16* __restrict__ wqkvb,
                               u16* __restrict__ wob) {
  int i = blockIdx.x * 256 + threadIdx.x;   // float4 index
  const float* src;
  u16* dst;
  if (i < (1 << 20)) {
    src = x; dst = xb;
  } else if (i < (1 << 20) + (3 << 18)) {
    i -= (1 << 20); src = wqkv; dst = wqkvb;
  } else {
    i -= (1 << 20) + (3 << 18); src = wo; dst = wob;
  }
  float4 v = ((const float4*)src)[i];
  ushort4 o;
  o.x = f2bf(v.x); o.y = f2bf(v.y); o.z = f2bf(v.z); o.w = f2bf(v.w);
  ((ushort4*)dst)[i] = o;
}

// ---- 128x128 bf16 MFMA GEMM, qkv^T: D = Wqkv(3072xK) . x(4096xK)^T
// Fused RoPE; outputs routed through an LDS transpose so ALL global
// writes are contiguous 128B rows.
__global__ __launch_bounds__(256) void gemm_qkv_kernel(
    const u16* __restrict__ A, const u16* __restrict__ B,
    u16* __restrict__ qb, u16* __restrict__ kb,
    u16* __restrict__ vbT, const float2* __restrict__ cstab) {
  const int K = 1024;
  __shared__ __align__(16) u16 As[128][32];
  __shared__ __align__(16) u16 Bs[128][32];
  __shared__ __align__(16) u16 Ts[128][136];   // transpose scratch (+8 pad)
  const int tid = threadIdx.x;
  const int wave = tid >> 6, lane = tid & 63;
  const int quad = lane >> 4, col = lane & 15;
  const int rowBase = blockIdx.x * 128;
  const int colBase = blockIdx.y * 128;
  const int wm = (wave >> 1) * 64, wn = (wave & 1) * 64;

  const int sRow = wave * 32 + (lane >> 2);
  const int sK = (lane & 3) * 8;
  const u16* gA = A + (size_t)(rowBase + sRow) * K + sK;
  const u16* gB = B + (size_t)(colBase + sRow) * K + sK;

  f32x4 acc[4][4];
#pragma unroll
  for (int i = 0; i < 4; ++i)
#pragma unroll
    for (int j = 0; j < 4; ++j)
      acc[i][j] = f32x4{0.f, 0.f, 0.f, 0.f};

  for (int kk = 0; kk < K; kk += 32) {
    __syncthreads();
    async16(gA + kk, &As[sRow][sK]);
    async16(gA + kk + 16 * K, &As[sRow + 16][sK]);
    async16(gB + kk, &Bs[sRow][sK]);
    async16(gB + kk + 16 * K, &Bs[sRow + 16][sK]);
    __syncthreads();
    bf16x8 af[4], bfr[4];
#pragma unroll
    for (int i = 0; i < 4; ++i)
      af[i] = *(const bf16x8*)&As[wm + i * 16 + col][quad * 8];
#pragma unroll
    for (int j = 0; j < 4; ++j)
      bfr[j] = *(const bf16x8*)&Bs[wn + j * 16 + col][quad * 8];
#pragma unroll
    for (int i = 0; i < 4; ++i)
#pragma unroll
      for (int j = 0; j < 4; ++j)
        acc[i][j] = mfma16(af[i], bfr[j], acc[i][j]);
  }

  const int sec = rowBase >> 10;   // block-uniform: 0=q 1=k 2=v

  if (sec < 2) {
    // RoPE in registers, write TRANSPOSED tile Ts[s_local][e_local]
#pragma unroll
    for (int j = 0; j < 4; ++j) {
      int sl = wn + j * 16 + col;
      int s = colBase + sl;
#pragma unroll
      for (int i = 0; i < 4; ++i) {
        int el = wm + i * 16 + quad * 4;
        int d = (rowBase + el) & 63;           // d % 4 == 0
        float v0 = acc[i][j][0], v1 = acc[i][j][1];
        float v2 = acc[i][j][2], v3 = acc[i][j][3];
        float2 cs0 = cstab[s * 32 + (d >> 1)];
        float2 cs1 = cstab[s * 32 + (d >> 1) + 1];
        ushort4 pk;
        pk.x = f2bf(v0 * cs0.x - v1 * cs0.y);
        pk.y = f2bf(v1 * cs0.x + v0 * cs0.y);
        pk.z = f2bf(v2 * cs1.x - v3 * cs1.y);
        pk.w = f2bf(v3 * cs1.x + v2 * cs1.y);
        *(ushort4*)&Ts[sl][el] = pk;           // 8B aligned
      }
    }
    __syncthreads();
    // coalesced store: thread = (s row, head half); 128B contiguous
    int sl = tid >> 1, hf = tid & 1;
    int hh = ((rowBase & 1023) >> 6) + hf;
    u16* dst = (sec == 0 ? qb : kb) + ((size_t)hh * SLEN + colBase + sl) * 64;
    const u16* srcp = &Ts[sl][hf * 64];
#pragma unroll
    for (int kq = 0; kq < 8; ++kq)
      ((int4*)dst)[kq] = ((const int4*)srcp)[kq];
  } else {
    // v: C-layout is already v^T[d][s]; write direct Ts[e_local][s_local]
#pragma unroll
    for (int j = 0; j < 4; ++j) {
      int sl = wn + j * 16 + col;
#pragma unroll
      for (int i = 0; i < 4; ++i) {
        int el = wm + i * 16 + quad * 4;
#pragma unroll
        for (int r = 0; r < 4; ++r)
          Ts[el + r][sl] = f2bf(acc[i][j][r]);
      }
    }
    __syncthreads();
    int el = tid >> 1, sh = tid & 1;
    int e = rowBase - 2048 + el;
    int hh = e >> 6, d = e & 63;
    u16* dst = vbT + (size_t)(hh * 64 + d) * SLEN + colBase + sh * 64;
    const u16* srcp = &Ts[el][sh * 64];
#pragma unroll
    for (int kq = 0; kq < 8; ++kq)
      ((int4*)dst)[kq] = ((const int4*)srcp)[kq];
  }
}

// ---- 128x64 bf16 MFMA GEMM, out = attn(4096xK) . Wo(1024xK)^T, fp32 out.
__global__ __launch_bounds__(256) void gemm_out_kernel(
    const u16* __restrict__ A, const u16* __restrict__ B,
    float* __restrict__ outf) {
  const int K = 1024;
  __shared__ __align__(16) u16 As[128][32];
  __shared__ __align__(16) u16 Bs[64][32];
  const int tid = threadIdx.x;
  const int wave = tid >> 6, lane = tid & 63;
  const int quad = lane >> 4, col = lane & 15;
  const int rowBase = blockIdx.x * 128;
  const int colBase = blockIdx.y * 64;

  const int sRow = wave * 32 + (lane >> 2);
  const int bRow = wave * 16 + (lane >> 2);
  const int sK = (lane & 3) * 8;
  const u16* gA = A + (size_t)(rowBase + sRow) * K + sK;
  const u16* gB = B + (size_t)(colBase + bRow) * K + sK;

  f32x4 acc[2][4];
#pragma unroll
  for (int i = 0; i < 2; ++i)
#pragma unroll
    for (int j = 0; j < 4; ++j)
      acc[i][j] = f32x4{0.f, 0.f, 0.f, 0.f};

  for (int kk = 0; kk < K; kk += 32) {
    __syncthreads();
    async16(gA + kk, &As[sRow][sK]);
    async16(gA + kk + 16 * K, &As[sRow + 16][sK]);
    async16(gB + kk, &Bs[bRow][sK]);
    __syncthreads();
    bf16x8 af[2], bfr[4];
#pragma unroll
    for (int i = 0; i < 2; ++i)
      af[i] = *(const bf16x8*)&As[wave * 32 + i * 16 + col][quad * 8];
#pragma unroll
    for (int j = 0; j < 4; ++j)
      bfr[j] = *(const bf16x8*)&Bs[j * 16 + col][quad * 8];
#pragma unroll
    for (int i = 0; i < 2; ++i)
#pragma unroll
      for (int j = 0; j < 4; ++j)
        acc[i][j] = mfma16(af[i], bfr[j], acc[i][j]);
  }

#pragma unroll
  for (int i = 0; i < 2; ++i) {
    int r0 = rowBase + wave * 32 + i * 16 + quad * 4;
#pragma unroll
    for (int j = 0; j < 4; ++j) {
      int cc = colBase + j * 16 + col;
#pragma unroll
      for (int r = 0; r < 4; ++r)
        outf[(size_t)(r0 + r) * DMODEL + cc] = acc[i][j][r];
    }
  }
}

// ---- causal flash attention v8: 64-row q-tiles, 2 waves/block (R6 tiling),
// SINGLE-buffered K/V m97-style (2 barriers/chunk) to shrink LDS 42->25.3KB
// and raise block residency; exposed stage-drain hidden by co-resident
// blocks. Grid (16 heads, 64 tiles) longest-first.
__global__ __launch_bounds__(128) void flash_kernel(
    const u16* __restrict__ qbuf, const u16* __restrict__ kbuf,
    const u16* __restrict__ vbT, u16* __restrict__ attn) {
  const int S = SLEN;
  const int h = blockIdx.x;
  const int tile = 63 - (int)blockIdx.y;       // long tiles first
  const int wave = threadIdx.x >> 6, lane = threadIdx.x & 63;
  const int quad = lane >> 4, col = lane & 15;
  const u16* Q = qbuf + (size_t)h * S * 64;
  const u16* Kh = kbuf + (size_t)h * S * 64;
  const u16* Vt = vbT + (size_t)h * 64 * S;

  __shared__ __align__(16) u16 Ks[64][64];
  __shared__ __align__(16) u16 Vs[64][64];
  __shared__ __align__(16) u16 Pld[2][2][16][72];  // [wave][strip]

  const int sr = lane >> 3;                    // 0..7
  const int sw = ((lane & 7) ^ sr) * 8;        // swizzled global seg
  const int dcol = (lane & 7) * 8;             // LDS seg = lane order
  const int segA = ((quad ^ (col & 7)) * 8);
  const int segB = (((quad ^ 4) ^ (col & 7)) * 8);

  const int nch = tile + 1;
  const int qrow0 = tile * 64 + wave * 32;

  bf16x8 qf0[2], qf1[2];
#pragma unroll
  for (int i = 0; i < 2; ++i) {
    const u16* qp = &Q[(size_t)(qrow0 + i * 16 + col) * 64 + quad * 8];
    qf0[i] = *(const bf16x8*)qp;
    qf1[i] = *(const bf16x8*)(qp + 32);
  }

  f32x4 o[2][4];
#pragma unroll
  for (int i = 0; i < 2; ++i)
#pragma unroll
    for (int n = 0; n < 4; ++n) o[i][n] = f32x4{0.f, 0.f, 0.f, 0.f};
  float lrow[2][4] = {{0.f, 0.f, 0.f, 0.f}, {0.f, 0.f, 0.f, 0.f}};

  for (int c = 0; c < nch; ++c) {
    const int k0 = c * 64;
    __syncthreads();        // previous chunk's readers done
    {
#pragma unroll
      for (int t = 0; t < 4; ++t) {
        int row = (t * 2 + wave) * 8 + sr;
        async16(Kh + (size_t)(k0 + row) * 64 + sw, &Ks[row][dcol]);
        async16(Vt + (size_t)row * S + k0 + sw, &Vs[row][dcol]);
      }
    }
    __syncthreads();        // stage drained

    bf16x8 kf0[4], kf1[4], vf0[4], vf1[4];
#pragma unroll
    for (int j = 0; j < 4; ++j) {
      kf0[j] = *(const bf16x8*)&Ks[16 * j + col][segA];
      kf1[j] = *(const bf16x8*)&Ks[16 * j + col][segB];
    }
#pragma unroll
    for (int n = 0; n < 4; ++n) {
      vf0[n] = *(const bf16x8*)&Vs[16 * n + col][segA];
      vf1[n] = *(const bf16x8*)&Vs[16 * n + col][segB];
    }
    const bool lastc = (c == nch - 1);
#pragma unroll
    for (int i = 0; i < 2; ++i) {
      f32x4 s[4];
#pragma unroll
      for (int j = 0; j < 4; ++j)
        s[j] = mfma16(qf1[i], kf1[j],
                      mfma16(qf0[i], kf0[j], f32x4{0.f, 0.f, 0.f, 0.f}));
      float p[4][4];
#pragma unroll
      for (int r = 0; r < 4; ++r) {
        const int qrel = wave * 32 + i * 16 + quad * 4 + r;  // row - tile*64
#pragma unroll
        for (int j = 0; j < 4; ++j) {
          float e = __expf(s[j][r] * 0.125f);
          if (lastc && (16 * j + col > qrel)) e = 0.f;
          p[j][r] = e;
        }
        lrow[i][r] += (p[0][r] + p[1][r]) + (p[2][r] + p[3][r]);
      }
#pragma unroll
      for (int j = 0; j < 4; ++j)
#pragma unroll
        for (int r = 0; r < 4; ++r)
          Pld[wave][i][quad * 4 + r][16 * j + col] = f2bf_trunc(p[j][r]);
      bf16x8 pa0 = *(const bf16x8*)&Pld[wave][i][col][quad * 8];
      bf16x8 pa1 = *(const bf16x8*)&Pld[wave][i][col][quad * 8 + 32];
#pragma unroll
      for (int n = 0; n < 4; ++n)
        o[i][n] = mfma16(pa1, vf1[n], mfma16(pa0, vf0[n], o[i][n]));
    }
  }

#pragma unroll
  for (int i = 0; i < 2; ++i) {
#pragma unroll
    for (int m = 1; m <= 8; m <<= 1)
#pragma unroll
      for (int r = 0; r < 4; ++r) lrow[i][r] += __shfl_xor(lrow[i][r], m);
#pragma unroll
    for (int r = 0; r < 4; ++r) {
      float inv = 1.0f / lrow[i][r];
      int row = qrow0 + i * 16 + quad * 4 + r;
      u16* dst = &attn[(size_t)row * DMODEL + h * 64 + col];
#pragma unroll
      for (int n = 0; n < 4; ++n) dst[16 * n] = f2bf(o[i][n][r] * inv);
    }
  }
}

extern "C" void kernel_launch(void* const* d_in, const int* in_sizes, int n_in,
                              void* d_out, int out_size, void* d_ws,
                              size_t ws_size, hipStream_t stream) {
  const float* x = (const float*)d_in[0];
  const int* tokpos = (const int*)d_in[1];
  const float* wqkv = (const float*)d_in[2];
  const float* wo = (const float*)d_in[3];
  float* out = (float*)d_out;

  char* ws = (char*)d_ws;
  u16* xb    = (u16*)(ws);
  u16* wqkvb = (u16*)(ws + ((size_t)8 << 20));
  u16* wob   = (u16*)(ws + ((size_t)14 << 20));
  u16* qb    = (u16*)(ws + ((size_t)16 << 20));
  u16* kb    = (u16*)(ws + ((size_t)24 << 20));
  u16* vbT   = (u16*)(ws + ((size_t)32 << 20));
  u16* attn  = (u16*)(ws + ((size_t)40 << 20));
  float2* cstab = (float2*)(ws + ((size_t)48 << 20));

  rope_tab_kernel<<<dim3(512), dim3(256), 0, stream>>>(tokpos, cstab);
  cvt_all_kernel<<<dim3(8192), dim3(256), 0, stream>>>(x, wqkv, wo, xb, wqkvb,
                                                       wob);
  gemm_qkv_kernel<<<dim3(24, 32), dim3(256), 0, stream>>>(
      wqkvb, xb, qb, kb, vbT, cstab);
  flash_kernel<<<dim3(16, 64), dim3(128), 0, stream>>>(qb, kb, vbT, attn);
  gemm_out_kernel<<<dim3(32, 16), dim3(256), 0, stream>>>(attn, wob, out);
}

// Round 9
// 232.472 us; speedup vs baseline: 1.1744x; 1.0598x over previous
//
#include <hip/hip_runtime.h>
#include <stdint.h>

typedef unsigned short u16;
typedef __attribute__((ext_vector_type(8))) short bf16x8;
typedef __attribute__((ext_vector_type(4))) float f32x4;

#define LN_THETA 9.210340371976184f
#define SLEN 4096
#define DMODEL 1024

__device__ __forceinline__ u16 f2bf(float f) {
  union { float f; unsigned u; } v; v.f = f;
  unsigned u = v.u;
  return (u16)((u + 0x7FFFu + ((u >> 16) & 1u)) >> 16);
}
__device__ __forceinline__ u16 f2bf_trunc(float f) {
  union { float f; unsigned u; } v; v.f = f;
  return (u16)(v.u >> 16);
}
__device__ __forceinline__ float bf2f(u16 b) {
  union { unsigned u; float f; } v; v.u = ((unsigned)b) << 16;
  return v.f;
}

__device__ __forceinline__ f32x4 mfma16(bf16x8 a, bf16x8 b, f32x4 c) {
  return __builtin_amdgcn_mfma_f32_16x16x32_bf16(a, b, c, 0, 0, 0);
}

__device__ __forceinline__ void async16(const u16* g, u16* l) {
  __builtin_amdgcn_global_load_lds(
      (const __attribute__((address_space(1))) unsigned int*)g,
      (__attribute__((address_space(3))) unsigned int*)l, 16, 0, 0);
}

// ---- RoPE table: tab[s*32+i] = (cos, sin)(pos[s] * theta^(-2i/64))
__global__ void rope_tab_kernel(const int* __restrict__ tokpos,
                                float2* __restrict__ tab) {
  int t = blockIdx.x * 256 + threadIdx.x;   // 0 .. 4096*32-1
  int s = t >> 5, i = t & 31;
  float inv = expf(-(float)(2 * i) * (LN_THETA / 64.0f));
  float ang = (float)tokpos[s] * inv;
  float sn, cs;
  sincosf(ang, &sn, &cs);
  tab[t] = make_float2(cs, sn);
}

// ---- fp32 -> bf16 (RNE), all three inputs in one launch
__global__ void cvt_all_kernel(const float* __restrict__ x,
                               const float* __restrict__ wqkv,
                               const float* __restrict__ wo,
                               u16* __restrict__ xb, u16* __restrict__ wqkvb,
                               u16* __restrict__ wob) {
  int i = blockIdx.x * 256 + threadIdx.x;   // float4 index
  const float* src;
  u16* dst;
  if (i < (1 << 20)) {
    src = x; dst = xb;
  } else if (i < (1 << 20) + (3 << 18)) {
    i -= (1 << 20); src = wqkv; dst = wqkvb;
  } else {
    i -= (1 << 20) + (3 << 18); src = wo; dst = wob;
  }
  float4 v = ((const float4*)src)[i];
  ushort4 o;
  o.x = f2bf(v.x); o.y = f2bf(v.y); o.z = f2bf(v.z); o.w = f2bf(v.w);
  ((ushort4*)dst)[i] = o;
}

// ---- 128x128 bf16 MFMA GEMM, qkv^T: D = Wqkv(3072xK) . x(4096xK)^T
// Fused RoPE; outputs routed through an LDS transpose so ALL global
// writes are contiguous 128B rows.
__global__ __launch_bounds__(256) void gemm_qkv_kernel(
    const u16* __restrict__ A, const u16* __restrict__ B,
    u16* __restrict__ qb, u16* __restrict__ kb,
    u16* __restrict__ vbT, const float2* __restrict__ cstab) {
  const int K = 1024;
  __shared__ __align__(16) u16 As[128][32];
  __shared__ __align__(16) u16 Bs[128][32];
  __shared__ __align__(16) u16 Ts[128][136];   // transpose scratch (+8 pad)
  const int tid = threadIdx.x;
  const int wave = tid >> 6, lane = tid & 63;
  const int quad = lane >> 4, col = lane & 15;
  const int rowBase = blockIdx.x * 128;
  const int colBase = blockIdx.y * 128;
  const int wm = (wave >> 1) * 64, wn = (wave & 1) * 64;

  const int sRow = wave * 32 + (lane >> 2);
  const int sK = (lane & 3) * 8;
  const u16* gA = A + (size_t)(rowBase + sRow) * K + sK;
  const u16* gB = B + (size_t)(colBase + sRow) * K + sK;

  f32x4 acc[4][4];
#pragma unroll
  for (int i = 0; i < 4; ++i)
#pragma unroll
    for (int j = 0; j < 4; ++j)
      acc[i][j] = f32x4{0.f, 0.f, 0.f, 0.f};

  for (int kk = 0; kk < K; kk += 32) {
    __syncthreads();
    async16(gA + kk, &As[sRow][sK]);
    async16(gA + kk + 16 * K, &As[sRow + 16][sK]);
    async16(gB + kk, &Bs[sRow][sK]);
    async16(gB + kk + 16 * K, &Bs[sRow + 16][sK]);
    __syncthreads();
    bf16x8 af[4], bfr[4];
#pragma unroll
    for (int i = 0; i < 4; ++i)
      af[i] = *(const bf16x8*)&As[wm + i * 16 + col][quad * 8];
#pragma unroll
    for (int j = 0; j < 4; ++j)
      bfr[j] = *(const bf16x8*)&Bs[wn + j * 16 + col][quad * 8];
#pragma unroll
    for (int i = 0; i < 4; ++i)
#pragma unroll
      for (int j = 0; j < 4; ++j)
        acc[i][j] = mfma16(af[i], bfr[j], acc[i][j]);
  }

  const int sec = rowBase >> 10;   // block-uniform: 0=q 1=k 2=v

  if (sec < 2) {
    // RoPE in registers, write TRANSPOSED tile Ts[s_local][e_local]
#pragma unroll
    for (int j = 0; j < 4; ++j) {
      int sl = wn + j * 16 + col;
      int s = colBase + sl;
#pragma unroll
      for (int i = 0; i < 4; ++i) {
        int el = wm + i * 16 + quad * 4;
        int d = (rowBase + el) & 63;           // d % 4 == 0
        float v0 = acc[i][j][0], v1 = acc[i][j][1];
        float v2 = acc[i][j][2], v3 = acc[i][j][3];
        float2 cs0 = cstab[s * 32 + (d >> 1)];
        float2 cs1 = cstab[s * 32 + (d >> 1) + 1];
        ushort4 pk;
        pk.x = f2bf(v0 * cs0.x - v1 * cs0.y);
        pk.y = f2bf(v1 * cs0.x + v0 * cs0.y);
        pk.z = f2bf(v2 * cs1.x - v3 * cs1.y);
        pk.w = f2bf(v3 * cs1.x + v2 * cs1.y);
        *(ushort4*)&Ts[sl][el] = pk;           // 8B aligned
      }
    }
    __syncthreads();
    // coalesced store: thread = (s row, head half); 128B contiguous
    int sl = tid >> 1, hf = tid & 1;
    int hh = ((rowBase & 1023) >> 6) + hf;
    u16* dst = (sec == 0 ? qb : kb) + ((size_t)hh * SLEN + colBase + sl) * 64;
    const u16* srcp = &Ts[sl][hf * 64];
#pragma unroll
    for (int kq = 0; kq < 8; ++kq)
      ((int4*)dst)[kq] = ((const int4*)srcp)[kq];
  } else {
    // v: C-layout is already v^T[d][s]; write direct Ts[e_local][s_local]
#pragma unroll
    for (int j = 0; j < 4; ++j) {
      int sl = wn + j * 16 + col;
#pragma unroll
      for (int i = 0; i < 4; ++i) {
        int el = wm + i * 16 + quad * 4;
#pragma unroll
        for (int r = 0; r < 4; ++r)
          Ts[el + r][sl] = f2bf(acc[i][j][r]);
      }
    }
    __syncthreads();
    int el = tid >> 1, sh = tid & 1;
    int e = rowBase - 2048 + el;
    int hh = e >> 6, d = e & 63;
    u16* dst = vbT + (size_t)(hh * 64 + d) * SLEN + colBase + sh * 64;
    const u16* srcp = &Ts[el][sh * 64];
#pragma unroll
    for (int kq = 0; kq < 8; ++kq)
      ((int4*)dst)[kq] = ((const int4*)srcp)[kq];
  }
}

// ---- 128x64 bf16 MFMA GEMM, out = attn(4096xK) . Wo(1024xK)^T, fp32 out.
__global__ __launch_bounds__(256) void gemm_out_kernel(
    const u16* __restrict__ A, const u16* __restrict__ B,
    float* __restrict__ outf) {
  const int K = 1024;
  __shared__ __align__(16) u16 As[128][32];
  __shared__ __align__(16) u16 Bs[64][32];
  const int tid = threadIdx.x;
  const int wave = tid >> 6, lane = tid & 63;
  const int quad = lane >> 4, col = lane & 15;
  const int rowBase = blockIdx.x * 128;
  const int colBase = blockIdx.y * 64;

  const int sRow = wave * 32 + (lane >> 2);
  const int bRow = wave * 16 + (lane >> 2);
  const int sK = (lane & 3) * 8;
  const u16* gA = A + (size_t)(rowBase + sRow) * K + sK;
  const u16* gB = B + (size_t)(colBase + bRow) * K + sK;

  f32x4 acc[2][4];
#pragma unroll
  for (int i = 0; i < 2; ++i)
#pragma unroll
    for (int j = 0; j < 4; ++j)
      acc[i][j] = f32x4{0.f, 0.f, 0.f, 0.f};

  for (int kk = 0; kk < K; kk += 32) {
    __syncthreads();
    async16(gA + kk, &As[sRow][sK]);
    async16(gA + kk + 16 * K, &As[sRow + 16][sK]);
    async16(gB + kk, &Bs[bRow][sK]);
    __syncthreads();
    bf16x8 af[2], bfr[4];
#pragma unroll
    for (int i = 0; i < 2; ++i)
      af[i] = *(const bf16x8*)&As[wave * 32 + i * 16 + col][quad * 8];
#pragma unroll
    for (int j = 0; j < 4; ++j)
      bfr[j] = *(const bf16x8*)&Bs[j * 16 + col][quad * 8];
#pragma unroll
    for (int i = 0; i < 2; ++i)
#pragma unroll
      for (int j = 0; j < 4; ++j)
        acc[i][j] = mfma16(af[i], bfr[j], acc[i][j]);
  }

#pragma unroll
  for (int i = 0; i < 2; ++i) {
    int r0 = rowBase + wave * 32 + i * 16 + quad * 4;
#pragma unroll
    for (int j = 0; j < 4; ++j) {
      int cc = colBase + j * 16 + col;
#pragma unroll
      for (int r = 0; r < 4; ++r)
        outf[(size_t)(r0 + r) * DMODEL + cc] = acc[i][j][r];
    }
  }
}

// ---- causal flash attention v9: SPLIT-K work items.
// Item = (head, 64-row q-tile, key segment of <=32 chunks). No-max softmax
// => partials combine by plain summation of (o, l). Tiles 0..31: 1 segment;
// tiles 32..63: 2 segments (chunks 0..31 / 32..tile). 96 items per head,
// grid (16, 96) = 1536 blocks = 6/CU (LDS 25.6KB), interleaved longest-first.
// Longest serial chain: 32 chunks (was 64). Partials: o as bf16, l as fp32.
__global__ __launch_bounds__(128) void flash_kernel(
    const u16* __restrict__ qbuf, const u16* __restrict__ kbuf,
    const u16* __restrict__ vbT, u16* __restrict__ po,
    float* __restrict__ pl) {
  const int S = SLEN;
  const int h = blockIdx.x;
  const int y = blockIdx.y;
  int tile, c0, c1;
  if (y < 32) {                       // tiles 32..63, segment 0 (32 chunks)
    tile = 32 + y; c0 = 0; c1 = 31;
  } else {
    int k = (y - 32) >> 1;
    if ((y - 32) & 1) { tile = 31 - k; c0 = 0; c1 = tile; }   // 1-seg tiles
    else { tile = 63 - k; c0 = 32; c1 = tile; }               // segment 1
  }
  const int id = (tile < 32) ? tile : (32 + 2 * (tile - 32) + (c0 ? 1 : 0));

  const int wave = threadIdx.x >> 6, lane = threadIdx.x & 63;
  const int quad = lane >> 4, col = lane & 15;
  const u16* Q = qbuf + (size_t)h * S * 64;
  const u16* Kh = kbuf + (size_t)h * S * 64;
  const u16* Vt = vbT + (size_t)h * 64 * S;

  __shared__ __align__(16) u16 Ks[64][64];
  __shared__ __align__(16) u16 Vs[64][64];
  __shared__ __align__(16) u16 Pld[2][2][16][72];  // [wave][strip]

  const int sr = lane >> 3;                    // 0..7
  const int sw = ((lane & 7) ^ sr) * 8;        // swizzled global seg
  const int dcol = (lane & 7) * 8;             // LDS seg = lane order
  const int segA = ((quad ^ (col & 7)) * 8);
  const int segB = (((quad ^ 4) ^ (col & 7)) * 8);

  const int qrow0 = tile * 64 + wave * 32;

  bf16x8 qf0[2], qf1[2];
#pragma unroll
  for (int i = 0; i < 2; ++i) {
    const u16* qp = &Q[(size_t)(qrow0 + i * 16 + col) * 64 + quad * 8];
    qf0[i] = *(const bf16x8*)qp;
    qf1[i] = *(const bf16x8*)(qp + 32);
  }

  f32x4 o[2][4];
#pragma unroll
  for (int i = 0; i < 2; ++i)
#pragma unroll
    for (int n = 0; n < 4; ++n) o[i][n] = f32x4{0.f, 0.f, 0.f, 0.f};
  float lrow[2][4] = {{0.f, 0.f, 0.f, 0.f}, {0.f, 0.f, 0.f, 0.f}};

  for (int c = c0; c <= c1; ++c) {
    const int k0 = c * 64;
    __syncthreads();        // previous chunk's readers done
    {
#pragma unroll
      for (int t = 0; t < 4; ++t) {
        int row = (t * 2 + wave) * 8 + sr;
        async16(Kh + (size_t)(k0 + row) * 64 + sw, &Ks[row][dcol]);
        async16(Vt + (size_t)row * S + k0 + sw, &Vs[row][dcol]);
      }
    }
    __syncthreads();        // stage drained

    bf16x8 kf0[4], kf1[4], vf0[4], vf1[4];
#pragma unroll
    for (int j = 0; j < 4; ++j) {
      kf0[j] = *(const bf16x8*)&Ks[16 * j + col][segA];
      kf1[j] = *(const bf16x8*)&Ks[16 * j + col][segB];
    }
#pragma unroll
    for (int n = 0; n < 4; ++n) {
      vf0[n] = *(const bf16x8*)&Vs[16 * n + col][segA];
      vf1[n] = *(const bf16x8*)&Vs[16 * n + col][segB];
    }
    const bool lastc = (c == tile);   // diagonal chunk
#pragma unroll
    for (int i = 0; i < 2; ++i) {
      f32x4 s[4];
#pragma unroll
      for (int j = 0; j < 4; ++j)
        s[j] = mfma16(qf1[i], kf1[j],
                      mfma16(qf0[i], kf0[j], f32x4{0.f, 0.f, 0.f, 0.f}));
      float p[4][4];
#pragma unroll
      for (int r = 0; r < 4; ++r) {
        const int qrel = wave * 32 + i * 16 + quad * 4 + r;  // row - tile*64
#pragma unroll
        for (int j = 0; j < 4; ++j) {
          float e = __expf(s[j][r] * 0.125f);
          if (lastc && (16 * j + col > qrel)) e = 0.f;
          p[j][r] = e;
        }
        lrow[i][r] += (p[0][r] + p[1][r]) + (p[2][r] + p[3][r]);
      }
#pragma unroll
      for (int j = 0; j < 4; ++j)
#pragma unroll
        for (int r = 0; r < 4; ++r)
          Pld[wave][i][quad * 4 + r][16 * j + col] = f2bf_trunc(p[j][r]);
      bf16x8 pa0 = *(const bf16x8*)&Pld[wave][i][col][quad * 8];
      bf16x8 pa1 = *(const bf16x8*)&Pld[wave][i][col][quad * 8 + 32];
#pragma unroll
      for (int n = 0; n < 4; ++n)
        o[i][n] = mfma16(pa1, vf1[n], mfma16(pa0, vf0[n], o[i][n]));
    }
  }

  // epilogue: write UNNORMALIZED partial o (bf16) and partial l (fp32)
  u16* pob = po + (((size_t)h * 96 + id) * 64) * 64;
  float* plb = pl + ((size_t)h * 96 + id) * 64;
#pragma unroll
  for (int i = 0; i < 2; ++i) {
#pragma unroll
    for (int m = 1; m <= 8; m <<= 1)
#pragma unroll
      for (int r = 0; r < 4; ++r) lrow[i][r] += __shfl_xor(lrow[i][r], m);
#pragma unroll
    for (int r = 0; r < 4; ++r) {
      int rowl = wave * 32 + i * 16 + quad * 4 + r;
      u16* dst = pob + (size_t)rowl * 64 + col;
#pragma unroll
      for (int n = 0; n < 4; ++n) dst[16 * n] = f2bf(o[i][n][r]);
      if (col == 0) plb[rowl] = lrow[i][r];
    }
  }
}

// ---- combine split-K partials: attn[row][h*64+dim] = sum(po)/sum(pl)
__global__ __launch_bounds__(256) void reduce_kernel(
    const u16* __restrict__ po, const float* __restrict__ pl,
    u16* __restrict__ attn) {
  const int h = blockIdx.x, tile = blockIdx.y;
  const int tid = threadIdx.x;
  const int row = tid >> 2, dg = (tid & 3) * 16;
  int id0, ns;
  if (tile < 32) { id0 = tile; ns = 1; }
  else { id0 = 32 + 2 * (tile - 32); ns = 2; }

  float acc[16];
#pragma unroll
  for (int q = 0; q < 16; ++q) acc[q] = 0.f;
  float l = 0.f;
  for (int s = 0; s < ns; ++s) {
    const size_t base = ((size_t)h * 96 + id0 + s) * 64;
    const u16* p = po + (base + row) * 64 + dg;
    l += pl[base + row];
#pragma unroll
    for (int q = 0; q < 16; ++q) acc[q] += bf2f(p[q]);
  }
  float inv = 1.0f / l;
  u16* dst = attn + (size_t)(tile * 64 + row) * DMODEL + h * 64 + dg;
  ushort4 o0, o1, o2, o3;
  o0.x = f2bf(acc[0] * inv);  o0.y = f2bf(acc[1] * inv);
  o0.z = f2bf(acc[2] * inv);  o0.w = f2bf(acc[3] * inv);
  o1.x = f2bf(acc[4] * inv);  o1.y = f2bf(acc[5] * inv);
  o1.z = f2bf(acc[6] * inv);  o1.w = f2bf(acc[7] * inv);
  o2.x = f2bf(acc[8] * inv);  o2.y = f2bf(acc[9] * inv);
  o2.z = f2bf(acc[10] * inv); o2.w = f2bf(acc[11] * inv);
  o3.x = f2bf(acc[12] * inv); o3.y = f2bf(acc[13] * inv);
  o3.z = f2bf(acc[14] * inv); o3.w = f2bf(acc[15] * inv);
  ((ushort4*)dst)[0] = o0; ((ushort4*)dst)[1] = o1;
  ((ushort4*)dst)[2] = o2; ((ushort4*)dst)[3] = o3;
}

extern "C" void kernel_launch(void* const* d_in, const int* in_sizes, int n_in,
                              void* d_out, int out_size, void* d_ws,
                              size_t ws_size, hipStream_t stream) {
  const float* x = (const float*)d_in[0];
  const int* tokpos = (const int*)d_in[1];
  const float* wqkv = (const float*)d_in[2];
  const float* wo = (const float*)d_in[3];
  float* out = (float*)d_out;

  char* ws = (char*)d_ws;
  u16* xb    = (u16*)(ws);
  u16* wqkvb = (u16*)(ws + ((size_t)8 << 20));
  u16* wob   = (u16*)(ws + ((size_t)14 << 20));
  u16* qb    = (u16*)(ws + ((size_t)16 << 20));
  u16* kb    = (u16*)(ws + ((size_t)24 << 20));
  u16* vbT   = (u16*)(ws + ((size_t)32 << 20));
  u16* attn  = (u16*)(ws + ((size_t)40 << 20));
  float2* cstab = (float2*)(ws + ((size_t)48 << 20));
  // split-K partials overlay xb/wqkvb (dead after gemm_qkv):
  u16* po    = (u16*)(ws);                       // 16*96*64*64*2B = 12.6MB
  float* pl  = (float*)(ws + ((size_t)13 << 20)); // 16*96*64*4B = 0.4MB

  rope_tab_kernel<<<dim3(512), dim3(256), 0, stream>>>(tokpos, cstab);
  cvt_all_kernel<<<dim3(8192), dim3(256), 0, stream>>>(x, wqkv, wo, xb, wqkvb,
                                                       wob);
  gemm_qkv_kernel<<<dim3(24, 32), dim3(256), 0, stream>>>(
      wqkvb, xb, qb, kb, vbT, cstab);
  flash_kernel<<<dim3(16, 96), dim3(128), 0, stream>>>(qb, kb, vbT, po, pl);
  reduce_kernel<<<dim3(16, 64), dim3(256), 0, stream>>>(po, pl, attn);
  gemm_out_kernel<<<dim3(32, 16), dim3(256), 0, stream>>>(attn, wob, out);
}

// Round 10
// 220.170 us; speedup vs baseline: 1.2400x; 1.0559x over previous
//
#include <hip/hip_runtime.h>
#include <stdint.h>

typedef unsigned short u16;
typedef __attribute__((ext_vector_type(8))) short bf16x8;
typedef __attribute__((ext_vector_type(4))) float f32x4;

#define LN_THETA 9.210340371976184f
#define SLEN 4096
#define DMODEL 1024

__device__ __forceinline__ u16 f2bf(float f) {
  union { float f; unsigned u; } v; v.f = f;
  unsigned u = v.u;
  return (u16)((u + 0x7FFFu + ((u >> 16) & 1u)) >> 16);
}
__device__ __forceinline__ u16 f2bf_trunc(float f) {
  union { float f; unsigned u; } v; v.f = f;
  return (u16)(v.u >> 16);
}
__device__ __forceinline__ float bf2f(u16 b) {
  union { unsigned u; float f; } v; v.u = ((unsigned)b) << 16;
  return v.f;
}

__device__ __forceinline__ f32x4 mfma16(bf16x8 a, bf16x8 b, f32x4 c) {
  return __builtin_amdgcn_mfma_f32_16x16x32_bf16(a, b, c, 0, 0, 0);
}

__device__ __forceinline__ void async16(const u16* g, u16* l) {
  __builtin_amdgcn_global_load_lds(
      (const __attribute__((address_space(1))) unsigned int*)g,
      (__attribute__((address_space(3))) unsigned int*)l, 16, 0, 0);
}

// ---- RoPE table: tab[s*32+i] = (cos, sin)(pos[s] * theta^(-2i/64))
__global__ void rope_tab_kernel(const int* __restrict__ tokpos,
                                float2* __restrict__ tab) {
  int t = blockIdx.x * 256 + threadIdx.x;   // 0 .. 4096*32-1
  int s = t >> 5, i = t & 31;
  float inv = expf(-(float)(2 * i) * (LN_THETA / 64.0f));
  float ang = (float)tokpos[s] * inv;
  float sn, cs;
  sincosf(ang, &sn, &cs);
  tab[t] = make_float2(cs, sn);
}

// ---- fp32 -> bf16 (RNE), all three inputs in one launch
__global__ void cvt_all_kernel(const float* __restrict__ x,
                               const float* __restrict__ wqkv,
                               const float* __restrict__ wo,
                               u16* __restrict__ xb, u16* __restrict__ wqkvb,
                               u16* __restrict__ wob) {
  int i = blockIdx.x * 256 + threadIdx.x;   // float4 index
  const float* src;
  u16* dst;
  if (i < (1 << 20)) {
    src = x; dst = xb;
  } else if (i < (1 << 20) + (3 << 18)) {
    i -= (1 << 20); src = wqkv; dst = wqkvb;
  } else {
    i -= (1 << 20) + (3 << 18); src = wo; dst = wob;
  }
  float4 v = ((const float4*)src)[i];
  ushort4 o;
  o.x = f2bf(v.x); o.y = f2bf(v.y); o.z = f2bf(v.z); o.w = f2bf(v.w);
  ((ushort4*)dst)[i] = o;
}

// ---- 128x128 bf16 MFMA GEMM, qkv^T, BK=64, XOR-8 swizzled staging.
// LDS union: As/Bs (32KB) overlap the 34.8KB Ts transpose scratch.
// Fused RoPE (q additionally pre-scaled by 0.125 = exact in bf16, so the
// flash kernel needs no per-score scale mul).
__global__ __launch_bounds__(256) void gemm_qkv_kernel(
    const u16* __restrict__ A, const u16* __restrict__ B,
    u16* __restrict__ qb, u16* __restrict__ kb,
    u16* __restrict__ vbT, const float2* __restrict__ cstab) {
  const int K = 1024;
  __shared__ __align__(16) char smem[128 * 136 * 2];   // 34816 B
  u16 (*As)[64] = (u16(*)[64])smem;                    // 16KB
  u16 (*Bs)[64] = (u16(*)[64])(smem + 16384);          // 16KB
  u16 (*Ts)[136] = (u16(*)[136])smem;                  // epilogue reuse
  const int tid = threadIdx.x;
  const int wave = tid >> 6, lane = tid & 63;
  const int quad = lane >> 4, col = lane & 15;
  const int rowBase = blockIdx.x * 128;
  const int colBase = blockIdx.y * 128;
  const int wm = (wave >> 1) * 64, wn = (wave & 1) * 64;

  // staging: lane covers row (wave*8 + lane>>3), src seg XOR-swizzled by row&7
  const int sr8 = lane >> 3;
  const int sseg = ((lane & 7) ^ sr8) * 8;
  const u16* gA = A + (size_t)(rowBase + wave * 8 + sr8) * K + sseg;
  const u16* gB = B + (size_t)(colBase + wave * 8 + sr8) * K + sseg;
  u16* ldsA = &As[wave * 8 + sr8][(lane & 7) * 8];
  u16* ldsB = &Bs[wave * 8 + sr8][(lane & 7) * 8];

  // fragment read segs (undo swizzle; frag row&7 == col&7)
  const int segh[2] = {((quad ^ (col & 7)) * 8), (((4 + quad) ^ (col & 7)) * 8)};

  f32x4 acc[4][4];
#pragma unroll
  for (int i = 0; i < 4; ++i)
#pragma unroll
    for (int j = 0; j < 4; ++j)
      acc[i][j] = f32x4{0.f, 0.f, 0.f, 0.f};

  for (int kk = 0; kk < K; kk += 64) {
    __syncthreads();
#pragma unroll
    for (int j = 0; j < 4; ++j) {
      async16(gA + (size_t)j * 32 * K + kk, ldsA + j * 32 * 64);
      async16(gB + (size_t)j * 32 * K + kk, ldsB + j * 32 * 64);
    }
    __syncthreads();
#pragma unroll
    for (int h = 0; h < 2; ++h) {
      bf16x8 af[4], bfr[4];
#pragma unroll
      for (int i = 0; i < 4; ++i)
        af[i] = *(const bf16x8*)&As[wm + i * 16 + col][segh[h]];
#pragma unroll
      for (int j = 0; j < 4; ++j)
        bfr[j] = *(const bf16x8*)&Bs[wn + j * 16 + col][segh[h]];
#pragma unroll
      for (int i = 0; i < 4; ++i)
#pragma unroll
        for (int j = 0; j < 4; ++j)
          acc[i][j] = mfma16(af[i], bfr[j], acc[i][j]);
    }
  }
  __syncthreads();   // all As/Bs reads done before Ts overwrites them

  const int sec = rowBase >> 10;   // block-uniform: 0=q 1=k 2=v

  if (sec < 2) {
    const float qs = (sec == 0) ? 0.125f : 1.0f;  // fold attn scale into q
#pragma unroll
    for (int j = 0; j < 4; ++j) {
      int sl = wn + j * 16 + col;
      int s = colBase + sl;
#pragma unroll
      for (int i = 0; i < 4; ++i) {
        int el = wm + i * 16 + quad * 4;
        int d = (rowBase + el) & 63;           // d % 4 == 0
        float v0 = acc[i][j][0], v1 = acc[i][j][1];
        float v2 = acc[i][j][2], v3 = acc[i][j][3];
        float2 cs0 = cstab[s * 32 + (d >> 1)];
        float2 cs1 = cstab[s * 32 + (d >> 1) + 1];
        ushort4 pk;
        pk.x = f2bf(qs * (v0 * cs0.x - v1 * cs0.y));
        pk.y = f2bf(qs * (v1 * cs0.x + v0 * cs0.y));
        pk.z = f2bf(qs * (v2 * cs1.x - v3 * cs1.y));
        pk.w = f2bf(qs * (v3 * cs1.x + v2 * cs1.y));
        *(ushort4*)&Ts[sl][el] = pk;           // 8B aligned
      }
    }
    __syncthreads();
    int sl = tid >> 1, hf = tid & 1;
    int hh = ((rowBase & 1023) >> 6) + hf;
    u16* dst = (sec == 0 ? qb : kb) + ((size_t)hh * SLEN + colBase + sl) * 64;
    const u16* srcp = &Ts[sl][hf * 64];
#pragma unroll
    for (int kq = 0; kq < 8; ++kq)
      ((int4*)dst)[kq] = ((const int4*)srcp)[kq];
  } else {
#pragma unroll
    for (int j = 0; j < 4; ++j) {
      int sl = wn + j * 16 + col;
#pragma unroll
      for (int i = 0; i < 4; ++i) {
        int el = wm + i * 16 + quad * 4;
#pragma unroll
        for (int r = 0; r < 4; ++r)
          Ts[el + r][sl] = f2bf(acc[i][j][r]);
      }
    }
    __syncthreads();
    int el = tid >> 1, sh = tid & 1;
    int e = rowBase - 2048 + el;
    int hh = e >> 6, d = e & 63;
    u16* dst = vbT + (size_t)(hh * 64 + d) * SLEN + colBase + sh * 64;
    const u16* srcp = &Ts[el][sh * 64];
#pragma unroll
    for (int kq = 0; kq < 8; ++kq)
      ((int4*)dst)[kq] = ((const int4*)srcp)[kq];
  }
}

// ---- 128x64 bf16 MFMA GEMM, out = attn(4096xK) . Wo(1024xK)^T, BK=64.
__global__ __launch_bounds__(256) void gemm_out_kernel(
    const u16* __restrict__ A, const u16* __restrict__ B,
    float* __restrict__ outf) {
  const int K = 1024;
  __shared__ __align__(16) u16 As[128][64];
  __shared__ __align__(16) u16 Bs[64][64];
  const int tid = threadIdx.x;
  const int wave = tid >> 6, lane = tid & 63;
  const int quad = lane >> 4, col = lane & 15;
  const int rowBase = blockIdx.x * 128;
  const int colBase = blockIdx.y * 64;

  const int sr8 = lane >> 3;
  const int sseg = ((lane & 7) ^ sr8) * 8;
  const u16* gA = A + (size_t)(rowBase + wave * 8 + sr8) * K + sseg;
  const u16* gB = B + (size_t)(colBase + wave * 8 + sr8) * K + sseg;
  u16* ldsA = &As[wave * 8 + sr8][(lane & 7) * 8];
  u16* ldsB = &Bs[wave * 8 + sr8][(lane & 7) * 8];

  const int segh[2] = {((quad ^ (col & 7)) * 8), (((4 + quad) ^ (col & 7)) * 8)};

  f32x4 acc[2][4];
#pragma unroll
  for (int i = 0; i < 2; ++i)
#pragma unroll
    for (int j = 0; j < 4; ++j)
      acc[i][j] = f32x4{0.f, 0.f, 0.f, 0.f};

  for (int kk = 0; kk < K; kk += 64) {
    __syncthreads();
#pragma unroll
    for (int j = 0; j < 4; ++j)
      async16(gA + (size_t)j * 32 * K + kk, ldsA + j * 32 * 64);
#pragma unroll
    for (int j = 0; j < 2; ++j)
      async16(gB + (size_t)j * 32 * K + kk, ldsB + j * 32 * 64);
    __syncthreads();
#pragma unroll
    for (int h = 0; h < 2; ++h) {
      bf16x8 af[2], bfr[4];
#pragma unroll
      for (int i = 0; i < 2; ++i)
        af[i] = *(const bf16x8*)&As[wave * 32 + i * 16 + col][segh[h]];
#pragma unroll
      for (int j = 0; j < 4; ++j)
        bfr[j] = *(const bf16x8*)&Bs[j * 16 + col][segh[h]];
#pragma unroll
      for (int i = 0; i < 2; ++i)
#pragma unroll
        for (int j = 0; j < 4; ++j)
          acc[i][j] = mfma16(af[i], bfr[j], acc[i][j]);
    }
  }

#pragma unroll
  for (int i = 0; i < 2; ++i) {
    int r0 = rowBase + wave * 32 + i * 16 + quad * 4;
#pragma unroll
    for (int j = 0; j < 4; ++j) {
      int cc = colBase + j * 16 + col;
#pragma unroll
      for (int r = 0; r < 4; ++r)
        outf[(size_t)(r0 + r) * DMODEL + cc] = acc[i][j][r];
    }
  }
}

// ---- causal flash attention v10: R9 split-K structure +
//  (a) scale folded into q (no per-score mul),
//  (b) l computed by MFMA vs ones-vector (no VALU adds, no end shuffles).
__global__ __launch_bounds__(128) void flash_kernel(
    const u16* __restrict__ qbuf, const u16* __restrict__ kbuf,
    const u16* __restrict__ vbT, u16* __restrict__ po,
    float* __restrict__ pl) {
  const int S = SLEN;
  const int h = blockIdx.x;
  const int y = blockIdx.y;
  int tile, c0, c1;
  if (y < 32) {                       // tiles 32..63, segment 0 (32 chunks)
    tile = 32 + y; c0 = 0; c1 = 31;
  } else {
    int k = (y - 32) >> 1;
    if ((y - 32) & 1) { tile = 31 - k; c0 = 0; c1 = tile; }   // 1-seg tiles
    else { tile = 63 - k; c0 = 32; c1 = tile; }               // segment 1
  }
  const int id = (tile < 32) ? tile : (32 + 2 * (tile - 32) + (c0 ? 1 : 0));

  const int wave = threadIdx.x >> 6, lane = threadIdx.x & 63;
  const int quad = lane >> 4, col = lane & 15;
  const u16* Q = qbuf + (size_t)h * S * 64;
  const u16* Kh = kbuf + (size_t)h * S * 64;
  const u16* Vt = vbT + (size_t)h * 64 * S;

  __shared__ __align__(16) u16 Ks[64][64];
  __shared__ __align__(16) u16 Vs[64][64];
  __shared__ __align__(16) u16 Pld[2][2][16][72];  // [wave][strip]

  const int sr = lane >> 3;
  const int sw = ((lane & 7) ^ sr) * 8;
  const int dcol = (lane & 7) * 8;
  const int segA = ((quad ^ (col & 7)) * 8);
  const int segB = (((quad ^ 4) ^ (col & 7)) * 8);

  const int qrow0 = tile * 64 + wave * 32;

  bf16x8 qf0[2], qf1[2];
#pragma unroll
  for (int i = 0; i < 2; ++i) {
    const u16* qp = &Q[(size_t)(qrow0 + i * 16 + col) * 64 + quad * 8];
    qf0[i] = *(const bf16x8*)qp;
    qf1[i] = *(const bf16x8*)(qp + 32);
  }

  const bf16x8 ones = {(short)0x3F80, (short)0x3F80, (short)0x3F80,
                       (short)0x3F80, (short)0x3F80, (short)0x3F80,
                       (short)0x3F80, (short)0x3F80};

  f32x4 o[2][4], lacc[2];
#pragma unroll
  for (int i = 0; i < 2; ++i) {
#pragma unroll
    for (int n = 0; n < 4; ++n) o[i][n] = f32x4{0.f, 0.f, 0.f, 0.f};
    lacc[i] = f32x4{0.f, 0.f, 0.f, 0.f};
  }

  for (int c = c0; c <= c1; ++c) {
    const int k0 = c * 64;
    __syncthreads();        // previous chunk's readers done
    {
#pragma unroll
      for (int t = 0; t < 4; ++t) {
        int row = (t * 2 + wave) * 8 + sr;
        async16(Kh + (size_t)(k0 + row) * 64 + sw, &Ks[row][dcol]);
        async16(Vt + (size_t)row * S + k0 + sw, &Vs[row][dcol]);
      }
    }
    __syncthreads();        // stage drained

    bf16x8 kf0[4], kf1[4], vf0[4], vf1[4];
#pragma unroll
    for (int j = 0; j < 4; ++j) {
      kf0[j] = *(const bf16x8*)&Ks[16 * j + col][segA];
      kf1[j] = *(const bf16x8*)&Ks[16 * j + col][segB];
    }
#pragma unroll
    for (int n = 0; n < 4; ++n) {
      vf0[n] = *(const bf16x8*)&Vs[16 * n + col][segA];
      vf1[n] = *(const bf16x8*)&Vs[16 * n + col][segB];
    }
    const bool lastc = (c == tile);   // diagonal chunk
#pragma unroll
    for (int i = 0; i < 2; ++i) {
      f32x4 s[4];
#pragma unroll
      for (int j = 0; j < 4; ++j)
        s[j] = mfma16(qf1[i], kf1[j],
                      mfma16(qf0[i], kf0[j], f32x4{0.f, 0.f, 0.f, 0.f}));
      float p[4][4];
#pragma unroll
      for (int r = 0; r < 4; ++r) {
        const int qrel = wave * 32 + i * 16 + quad * 4 + r;  // row - tile*64
#pragma unroll
        for (int j = 0; j < 4; ++j) {
          float e = __expf(s[j][r]);          // scale pre-folded into q
          if (lastc && (16 * j + col > qrel)) e = 0.f;
          p[j][r] = e;
        }
      }
#pragma unroll
      for (int j = 0; j < 4; ++j)
#pragma unroll
        for (int r = 0; r < 4; ++r)
          Pld[wave][i][quad * 4 + r][16 * j + col] = f2bf_trunc(p[j][r]);
      bf16x8 pa0 = *(const bf16x8*)&Pld[wave][i][col][quad * 8];
      bf16x8 pa1 = *(const bf16x8*)&Pld[wave][i][col][quad * 8 + 32];
      lacc[i] = mfma16(pa1, ones, mfma16(pa0, ones, lacc[i]));
#pragma unroll
      for (int n = 0; n < 4; ++n)
        o[i][n] = mfma16(pa1, vf1[n], mfma16(pa0, vf0[n], o[i][n]));
    }
  }

  // epilogue: write UNNORMALIZED partial o (bf16) and partial l (fp32).
  // lacc[i][r] already holds sum over k (replicated across cols).
  u16* pob = po + (((size_t)h * 96 + id) * 64) * 64;
  float* plb = pl + ((size_t)h * 96 + id) * 64;
#pragma unroll
  for (int i = 0; i < 2; ++i) {
#pragma unroll
    for (int r = 0; r < 4; ++r) {
      int rowl = wave * 32 + i * 16 + quad * 4 + r;
      u16* dst = pob + (size_t)rowl * 64 + col;
#pragma unroll
      for (int n = 0; n < 4; ++n) dst[16 * n] = f2bf(o[i][n][r]);
      if (col == 0) plb[rowl] = lacc[i][r];
    }
  }
}

// ---- combine split-K partials: attn[row][h*64+dim] = sum(po)/sum(pl)
__global__ __launch_bounds__(256) void reduce_kernel(
    const u16* __restrict__ po, const float* __restrict__ pl,
    u16* __restrict__ attn) {
  const int h = blockIdx.x, tile = blockIdx.y;
  const int tid = threadIdx.x;
  const int row = tid >> 2, dg = (tid & 3) * 16;
  int id0, ns;
  if (tile < 32) { id0 = tile; ns = 1; }
  else { id0 = 32 + 2 * (tile - 32); ns = 2; }

  float acc[16];
#pragma unroll
  for (int q = 0; q < 16; ++q) acc[q] = 0.f;
  float l = 0.f;
  for (int s = 0; s < ns; ++s) {
    const size_t base = ((size_t)h * 96 + id0 + s) * 64;
    const u16* p = po + (base + row) * 64 + dg;
    l += pl[base + row];
#pragma unroll
    for (int q = 0; q < 16; ++q) acc[q] += bf2f(p[q]);
  }
  float inv = 1.0f / l;
  u16* dst = attn + (size_t)(tile * 64 + row) * DMODEL + h * 64 + dg;
  ushort4 o0, o1, o2, o3;
  o0.x = f2bf(acc[0] * inv);  o0.y = f2bf(acc[1] * inv);
  o0.z = f2bf(acc[2] * inv);  o0.w = f2bf(acc[3] * inv);
  o1.x = f2bf(acc[4] * inv);  o1.y = f2bf(acc[5] * inv);
  o1.z = f2bf(acc[6] * inv);  o1.w = f2bf(acc[7] * inv);
  o2.x = f2bf(acc[8] * inv);  o2.y = f2bf(acc[9] * inv);
  o2.z = f2bf(acc[10] * inv); o2.w = f2bf(acc[11] * inv);
  o3.x = f2bf(acc[12] * inv); o3.y = f2bf(acc[13] * inv);
  o3.z = f2bf(acc[14] * inv); o3.w = f2bf(acc[15] * inv);
  ((ushort4*)dst)[0] = o0; ((ushort4*)dst)[1] = o1;
  ((ushort4*)dst)[2] = o2; ((ushort4*)dst)[3] = o3;
}

extern "C" void kernel_launch(void* const* d_in, const int* in_sizes, int n_in,
                              void* d_out, int out_size, void* d_ws,
                              size_t ws_size, hipStream_t stream) {
  const float* x = (const float*)d_in[0];
  const int* tokpos = (const int*)d_in[1];
  const float* wqkv = (const float*)d_in[2];
  const float* wo = (const float*)d_in[3];
  float* out = (float*)d_out;

  char* ws = (char*)d_ws;
  u16* xb    = (u16*)(ws);
  u16* wqkvb = (u16*)(ws + ((size_t)8 << 20));
  u16* wob   = (u16*)(ws + ((size_t)14 << 20));
  u16* qb    = (u16*)(ws + ((size_t)16 << 20));
  u16* kb    = (u16*)(ws + ((size_t)24 << 20));
  u16* vbT   = (u16*)(ws + ((size_t)32 << 20));
  u16* attn  = (u16*)(ws + ((size_t)40 << 20));
  float2* cstab = (float2*)(ws + ((size_t)48 << 20));
  // split-K partials overlay xb/wqkvb (dead after gemm_qkv):
  u16* po    = (u16*)(ws);                        // 12.6MB
  float* pl  = (float*)(ws + ((size_t)13 << 20)); // 0.4MB

  rope_tab_kernel<<<dim3(512), dim3(256), 0, stream>>>(tokpos, cstab);
  cvt_all_kernel<<<dim3(8192), dim3(256), 0, stream>>>(x, wqkv, wo, xb, wqkvb,
                                                       wob);
  gemm_qkv_kernel<<<dim3(24, 32), dim3(256), 0, stream>>>(
      wqkvb, xb, qb, kb, vbT, cstab);
  flash_kernel<<<dim3(16, 96), dim3(128), 0, stream>>>(qb, kb, vbT, po, pl);
  reduce_kernel<<<dim3(16, 64), dim3(256), 0, stream>>>(po, pl, attn);
  gemm_out_kernel<<<dim3(32, 16), dim3(256), 0, stream>>>(attn, wob, out);
}

// Round 11
// 210.394 us; speedup vs baseline: 1.2976x; 1.0465x over previous
//
#include <hip/hip_runtime.h>
#include <stdint.h>

typedef unsigned short u16;
typedef __attribute__((ext_vector_type(8))) short bf16x8;
typedef __attribute__((ext_vector_type(4))) float f32x4;

#define LN_THETA 9.210340371976184f
#define SLEN 4096
#define DMODEL 1024

__device__ __forceinline__ u16 f2bf(float f) {
  union { float f; unsigned u; } v; v.f = f;
  unsigned u = v.u;
  return (u16)((u + 0x7FFFu + ((u >> 16) & 1u)) >> 16);
}
__device__ __forceinline__ u16 f2bf_trunc(float f) {
  union { float f; unsigned u; } v; v.f = f;
  return (u16)(v.u >> 16);
}
__device__ __forceinline__ float bf2f(u16 b) {
  union { unsigned u; float f; } v; v.u = ((unsigned)b) << 16;
  return v.f;
}
__device__ __forceinline__ float fexp2(float x) {
#if __has_builtin(__builtin_amdgcn_exp2f)
  return __builtin_amdgcn_exp2f(x);
#else
  return exp2f(x);
#endif
}

__device__ __forceinline__ f32x4 mfma16(bf16x8 a, bf16x8 b, f32x4 c) {
  return __builtin_amdgcn_mfma_f32_16x16x32_bf16(a, b, c, 0, 0, 0);
}

__device__ __forceinline__ void async16(const u16* g, u16* l) {
  __builtin_amdgcn_global_load_lds(
      (const __attribute__((address_space(1))) unsigned int*)g,
      (__attribute__((address_space(3))) unsigned int*)l, 16, 0, 0);
}

// ---- prep: RoPE table (blocks 0..511) + fp32->bf16 converts (rest)
__global__ void prep_kernel(const int* __restrict__ tokpos,
                            float2* __restrict__ tab,
                            const float* __restrict__ x,
                            const float* __restrict__ wqkv,
                            const float* __restrict__ wo,
                            u16* __restrict__ xb, u16* __restrict__ wqkvb,
                            u16* __restrict__ wob) {
  if (blockIdx.x < 512) {
    int t = blockIdx.x * 256 + threadIdx.x;   // 0 .. 4096*32-1
    int s = t >> 5, i = t & 31;
    float inv = expf(-(float)(2 * i) * (LN_THETA / 64.0f));
    float ang = (float)tokpos[s] * inv;
    float sn, cs;
    sincosf(ang, &sn, &cs);
    tab[t] = make_float2(cs, sn);
    return;
  }
  int i = (blockIdx.x - 512) * 256 + threadIdx.x;   // float4 index
  const float* src;
  u16* dst;
  if (i < (1 << 20)) {
    src = x; dst = xb;
  } else if (i < (1 << 20) + (3 << 18)) {
    i -= (1 << 20); src = wqkv; dst = wqkvb;
  } else {
    i -= (1 << 20) + (3 << 18); src = wo; dst = wob;
  }
  float4 v = ((const float4*)src)[i];
  ushort4 o;
  o.x = f2bf(v.x); o.y = f2bf(v.y); o.z = f2bf(v.z); o.w = f2bf(v.w);
  ((ushort4*)dst)[i] = o;
}

// ---- 128x128 bf16 MFMA GEMM, qkv^T, BK=64, XOR-8 swizzled staging.
// LDS union: As/Bs (32KB) overlap the 34.8KB Ts transpose scratch.
// Fused RoPE; q pre-scaled by 0.125*log2(e) so flash uses raw exp2.
__global__ __launch_bounds__(256) void gemm_qkv_kernel(
    const u16* __restrict__ A, const u16* __restrict__ B,
    u16* __restrict__ qb, u16* __restrict__ kb,
    u16* __restrict__ vbT, const float2* __restrict__ cstab) {
  const int K = 1024;
  __shared__ __align__(16) char smem[128 * 136 * 2];   // 34816 B
  u16 (*As)[64] = (u16(*)[64])smem;                    // 16KB
  u16 (*Bs)[64] = (u16(*)[64])(smem + 16384);          // 16KB
  u16 (*Ts)[136] = (u16(*)[136])smem;                  // epilogue reuse
  const int tid = threadIdx.x;
  const int wave = tid >> 6, lane = tid & 63;
  const int quad = lane >> 4, col = lane & 15;
  const int rowBase = blockIdx.x * 128;
  const int colBase = blockIdx.y * 128;
  const int wm = (wave >> 1) * 64, wn = (wave & 1) * 64;

  const int sr8 = lane >> 3;
  const int sseg = ((lane & 7) ^ sr8) * 8;
  const u16* gA = A + (size_t)(rowBase + wave * 8 + sr8) * K + sseg;
  const u16* gB = B + (size_t)(colBase + wave * 8 + sr8) * K + sseg;
  u16* ldsA = &As[wave * 8 + sr8][(lane & 7) * 8];
  u16* ldsB = &Bs[wave * 8 + sr8][(lane & 7) * 8];

  const int segh[2] = {((quad ^ (col & 7)) * 8), (((4 + quad) ^ (col & 7)) * 8)};

  f32x4 acc[4][4];
#pragma unroll
  for (int i = 0; i < 4; ++i)
#pragma unroll
    for (int j = 0; j < 4; ++j)
      acc[i][j] = f32x4{0.f, 0.f, 0.f, 0.f};

  for (int kk = 0; kk < K; kk += 64) {
    __syncthreads();
#pragma unroll
    for (int j = 0; j < 4; ++j) {
      async16(gA + (size_t)j * 32 * K + kk, ldsA + j * 32 * 64);
      async16(gB + (size_t)j * 32 * K + kk, ldsB + j * 32 * 64);
    }
    __syncthreads();
#pragma unroll
    for (int h = 0; h < 2; ++h) {
      bf16x8 af[4], bfr[4];
#pragma unroll
      for (int i = 0; i < 4; ++i)
        af[i] = *(const bf16x8*)&As[wm + i * 16 + col][segh[h]];
#pragma unroll
      for (int j = 0; j < 4; ++j)
        bfr[j] = *(const bf16x8*)&Bs[wn + j * 16 + col][segh[h]];
#pragma unroll
      for (int i = 0; i < 4; ++i)
#pragma unroll
        for (int j = 0; j < 4; ++j)
          acc[i][j] = mfma16(af[i], bfr[j], acc[i][j]);
    }
  }
  __syncthreads();   // all As/Bs reads done before Ts overwrites them

  const int sec = rowBase >> 10;   // block-uniform: 0=q 1=k 2=v

  if (sec < 2) {
    // q: fold attn scale AND log2(e) so flash does p = exp2(s)
    const float qs = (sec == 0) ? 0.125f * 1.4426950408889634f : 1.0f;
#pragma unroll
    for (int j = 0; j < 4; ++j) {
      int sl = wn + j * 16 + col;
      int s = colBase + sl;
#pragma unroll
      for (int i = 0; i < 4; ++i) {
        int el = wm + i * 16 + quad * 4;
        int d = (rowBase + el) & 63;           // d % 4 == 0
        float v0 = acc[i][j][0], v1 = acc[i][j][1];
        float v2 = acc[i][j][2], v3 = acc[i][j][3];
        float2 cs0 = cstab[s * 32 + (d >> 1)];
        float2 cs1 = cstab[s * 32 + (d >> 1) + 1];
        ushort4 pk;
        pk.x = f2bf(qs * (v0 * cs0.x - v1 * cs0.y));
        pk.y = f2bf(qs * (v1 * cs0.x + v0 * cs0.y));
        pk.z = f2bf(qs * (v2 * cs1.x - v3 * cs1.y));
        pk.w = f2bf(qs * (v3 * cs1.x + v2 * cs1.y));
        *(ushort4*)&Ts[sl][el] = pk;           // 8B aligned
      }
    }
    __syncthreads();
    int sl = tid >> 1, hf = tid & 1;
    int hh = ((rowBase & 1023) >> 6) + hf;
    u16* dst = (sec == 0 ? qb : kb) + ((size_t)hh * SLEN + colBase + sl) * 64;
    const u16* srcp = &Ts[sl][hf * 64];
#pragma unroll
    for (int kq = 0; kq < 8; ++kq)
      ((int4*)dst)[kq] = ((const int4*)srcp)[kq];
  } else {
#pragma unroll
    for (int j = 0; j < 4; ++j) {
      int sl = wn + j * 16 + col;
#pragma unroll
      for (int i = 0; i < 4; ++i) {
        int el = wm + i * 16 + quad * 4;
#pragma unroll
        for (int r = 0; r < 4; ++r)
          Ts[el + r][sl] = f2bf(acc[i][j][r]);
      }
    }
    __syncthreads();
    int el = tid >> 1, sh = tid & 1;
    int e = rowBase - 2048 + el;
    int hh = e >> 6, d = e & 63;
    u16* dst = vbT + (size_t)(hh * 64 + d) * SLEN + colBase + sh * 64;
    const u16* srcp = &Ts[el][sh * 64];
#pragma unroll
    for (int kq = 0; kq < 8; ++kq)
      ((int4*)dst)[kq] = ((const int4*)srcp)[kq];
  }
}

// ---- 128x64 bf16 MFMA GEMM, out = attn(4096xK) . Wo(1024xK)^T, BK=64.
__global__ __launch_bounds__(256) void gemm_out_kernel(
    const u16* __restrict__ A, const u16* __restrict__ B,
    float* __restrict__ outf) {
  const int K = 1024;
  __shared__ __align__(16) u16 As[128][64];
  __shared__ __align__(16) u16 Bs[64][64];
  const int tid = threadIdx.x;
  const int wave = tid >> 6, lane = tid & 63;
  const int quad = lane >> 4, col = lane & 15;
  const int rowBase = blockIdx.x * 128;
  const int colBase = blockIdx.y * 64;

  const int sr8 = lane >> 3;
  const int sseg = ((lane & 7) ^ sr8) * 8;
  const u16* gA = A + (size_t)(rowBase + wave * 8 + sr8) * K + sseg;
  const u16* gB = B + (size_t)(colBase + wave * 8 + sr8) * K + sseg;
  u16* ldsA = &As[wave * 8 + sr8][(lane & 7) * 8];
  u16* ldsB = &Bs[wave * 8 + sr8][(lane & 7) * 8];

  const int segh[2] = {((quad ^ (col & 7)) * 8), (((4 + quad) ^ (col & 7)) * 8)};

  f32x4 acc[2][4];
#pragma unroll
  for (int i = 0; i < 2; ++i)
#pragma unroll
    for (int j = 0; j < 4; ++j)
      acc[i][j] = f32x4{0.f, 0.f, 0.f, 0.f};

  for (int kk = 0; kk < K; kk += 64) {
    __syncthreads();
#pragma unroll
    for (int j = 0; j < 4; ++j)
      async16(gA + (size_t)j * 32 * K + kk, ldsA + j * 32 * 64);
#pragma unroll
    for (int j = 0; j < 2; ++j)
      async16(gB + (size_t)j * 32 * K + kk, ldsB + j * 32 * 64);
    __syncthreads();
#pragma unroll
    for (int h = 0; h < 2; ++h) {
      bf16x8 af[2], bfr[4];
#pragma unroll
      for (int i = 0; i < 2; ++i)
        af[i] = *(const bf16x8*)&As[wave * 32 + i * 16 + col][segh[h]];
#pragma unroll
      for (int j = 0; j < 4; ++j)
        bfr[j] = *(const bf16x8*)&Bs[j * 16 + col][segh[h]];
#pragma unroll
      for (int i = 0; i < 2; ++i)
#pragma unroll
        for (int j = 0; j < 4; ++j)
          acc[i][j] = mfma16(af[i], bfr[j], acc[i][j]);
    }
  }

#pragma unroll
  for (int i = 0; i < 2; ++i) {
    int r0 = rowBase + wave * 32 + i * 16 + quad * 4;
#pragma unroll
    for (int j = 0; j < 4; ++j) {
      int cc = colBase + j * 16 + col;
#pragma unroll
      for (int r = 0; r < 4; ++r)
        outf[(size_t)(r0 + r) * DMODEL + cc] = acc[i][j][r];
    }
  }
}

// ---- causal flash attention v11: split-K items (R9 decode), 4 waves/block,
// ONE 16-row strip per wave (was 2 strips/wave). Per-wave chunk work halves;
// waves/CU doubles (6 blocks x 4 waves = 24 waves/CU at launch) to hide the
// chunk chain. LDS 25.6KB unchanged.
__global__ __launch_bounds__(256) void flash_kernel(
    const u16* __restrict__ qbuf, const u16* __restrict__ kbuf,
    const u16* __restrict__ vbT, u16* __restrict__ po,
    float* __restrict__ pl) {
  const int S = SLEN;
  const int h = blockIdx.x;
  const int y = blockIdx.y;
  int tile, c0, c1;
  if (y < 32) {                       // tiles 32..63, segment 0 (32 chunks)
    tile = 32 + y; c0 = 0; c1 = 31;
  } else {
    int k = (y - 32) >> 1;
    if ((y - 32) & 1) { tile = 31 - k; c0 = 0; c1 = tile; }   // 1-seg tiles
    else { tile = 63 - k; c0 = 32; c1 = tile; }               // segment 1
  }
  const int id = (tile < 32) ? tile : (32 + 2 * (tile - 32) + (c0 ? 1 : 0));

  const int wave = threadIdx.x >> 6, lane = threadIdx.x & 63;
  const int quad = lane >> 4, col = lane & 15;
  const u16* Q = qbuf + (size_t)h * S * 64;
  const u16* Kh = kbuf + (size_t)h * S * 64;
  const u16* Vt = vbT + (size_t)h * 64 * S;

  __shared__ __align__(16) u16 Ks[64][64];
  __shared__ __align__(16) u16 Vs[64][64];
  __shared__ __align__(16) u16 Pld[4][16][72];   // [wave], 1 strip each

  const int sr = lane >> 3;
  const int sw = ((lane & 7) ^ sr) * 8;
  const int dcol = (lane & 7) * 8;
  const int segA = ((quad ^ (col & 7)) * 8);
  const int segB = (((quad ^ 4) ^ (col & 7)) * 8);

  const int qrow0 = tile * 64 + wave * 16;

  bf16x8 qf0, qf1;
  {
    const u16* qp = &Q[(size_t)(qrow0 + col) * 64 + quad * 8];
    qf0 = *(const bf16x8*)qp;
    qf1 = *(const bf16x8*)(qp + 32);
  }

  const bf16x8 ones = {(short)0x3F80, (short)0x3F80, (short)0x3F80,
                       (short)0x3F80, (short)0x3F80, (short)0x3F80,
                       (short)0x3F80, (short)0x3F80};

  f32x4 o[4], lacc;
#pragma unroll
  for (int n = 0; n < 4; ++n) o[n] = f32x4{0.f, 0.f, 0.f, 0.f};
  lacc = f32x4{0.f, 0.f, 0.f, 0.f};

  for (int c = c0; c <= c1; ++c) {
    const int k0 = c * 64;
    __syncthreads();        // previous chunk's readers done
    {
#pragma unroll
      for (int t = 0; t < 2; ++t) {
        int row = wave * 16 + t * 8 + sr;
        async16(Kh + (size_t)(k0 + row) * 64 + sw, &Ks[row][dcol]);
        async16(Vt + (size_t)row * S + k0 + sw, &Vs[row][dcol]);
      }
    }
    __syncthreads();        // stage drained

    bf16x8 kf0[4], kf1[4], vf0[4], vf1[4];
#pragma unroll
    for (int j = 0; j < 4; ++j) {
      kf0[j] = *(const bf16x8*)&Ks[16 * j + col][segA];
      kf1[j] = *(const bf16x8*)&Ks[16 * j + col][segB];
    }
#pragma unroll
    for (int n = 0; n < 4; ++n) {
      vf0[n] = *(const bf16x8*)&Vs[16 * n + col][segA];
      vf1[n] = *(const bf16x8*)&Vs[16 * n + col][segB];
    }
    const bool lastc = (c == tile);   // diagonal chunk
    f32x4 s[4];
#pragma unroll
    for (int j = 0; j < 4; ++j)
      s[j] = mfma16(qf1, kf1[j],
                    mfma16(qf0, kf0[j], f32x4{0.f, 0.f, 0.f, 0.f}));
    float p[4][4];
#pragma unroll
    for (int r = 0; r < 4; ++r) {
      const int qabs = qrow0 + quad * 4 + r;
#pragma unroll
      for (int j = 0; j < 4; ++j) {
        float e = fexp2(s[j][r]);       // scale & log2e pre-folded into q
        if (lastc && (k0 + 16 * j + col > qabs)) e = 0.f;
        p[j][r] = e;
      }
    }
#pragma unroll
    for (int j = 0; j < 4; ++j)
#pragma unroll
      for (int r = 0; r < 4; ++r)
        Pld[wave][quad * 4 + r][16 * j + col] = f2bf_trunc(p[j][r]);
    bf16x8 pa0 = *(const bf16x8*)&Pld[wave][col][quad * 8];
    bf16x8 pa1 = *(const bf16x8*)&Pld[wave][col][quad * 8 + 32];
    lacc = mfma16(pa1, ones, mfma16(pa0, ones, lacc));
#pragma unroll
    for (int n = 0; n < 4; ++n)
      o[n] = mfma16(pa1, vf1[n], mfma16(pa0, vf0[n], o[n]));
  }

  // epilogue: write UNNORMALIZED partial o (bf16) and partial l (fp32)
  u16* pob = po + (((size_t)h * 96 + id) * 64) * 64;
  float* plb = pl + ((size_t)h * 96 + id) * 64;
#pragma unroll
  for (int r = 0; r < 4; ++r) {
    int rowl = wave * 16 + quad * 4 + r;
    u16* dst = pob + (size_t)rowl * 64 + col;
#pragma unroll
    for (int n = 0; n < 4; ++n) dst[16 * n] = f2bf(o[n][r]);
    if (col == 0) plb[rowl] = lacc[r];
  }
}

// ---- combine split-K partials: attn[row][h*64+dim] = sum(po)/sum(pl)
__global__ __launch_bounds__(256) void reduce_kernel(
    const u16* __restrict__ po, const float* __restrict__ pl,
    u16* __restrict__ attn) {
  const int h = blockIdx.x, tile = blockIdx.y;
  const int tid = threadIdx.x;
  const int row = tid >> 2, dg = (tid & 3) * 16;
  int id0, ns;
  if (tile < 32) { id0 = tile; ns = 1; }
  else { id0 = 32 + 2 * (tile - 32); ns = 2; }

  float acc[16];
#pragma unroll
  for (int q = 0; q < 16; ++q) acc[q] = 0.f;
  float l = 0.f;
  for (int s = 0; s < ns; ++s) {
    const size_t base = ((size_t)h * 96 + id0 + s) * 64;
    const u16* p = po + (base + row) * 64 + dg;
    l += pl[base + row];
#pragma unroll
    for (int q = 0; q < 16; ++q) acc[q] += bf2f(p[q]);
  }
  float inv = 1.0f / l;
  u16* dst = attn + (size_t)(tile * 64 + row) * DMODEL + h * 64 + dg;
  ushort4 o0, o1, o2, o3;
  o0.x = f2bf(acc[0] * inv);  o0.y = f2bf(acc[1] * inv);
  o0.z = f2bf(acc[2] * inv);  o0.w = f2bf(acc[3] * inv);
  o1.x = f2bf(acc[4] * inv);  o1.y = f2bf(acc[5] * inv);
  o1.z = f2bf(acc[6] * inv);  o1.w = f2bf(acc[7] * inv);
  o2.x = f2bf(acc[8] * inv);  o2.y = f2bf(acc[9] * inv);
  o2.z = f2bf(acc[10] * inv); o2.w = f2bf(acc[11] * inv);
  o3.x = f2bf(acc[12] * inv); o3.y = f2bf(acc[13] * inv);
  o3.z = f2bf(acc[14] * inv); o3.w = f2bf(acc[15] * inv);
  ((ushort4*)dst)[0] = o0; ((ushort4*)dst)[1] = o1;
  ((ushort4*)dst)[2] = o2; ((ushort4*)dst)[3] = o3;
}

extern "C" void kernel_launch(void* const* d_in, const int* in_sizes, int n_in,
                              void* d_out, int out_size, void* d_ws,
                              size_t ws_size, hipStream_t stream) {
  const float* x = (const float*)d_in[0];
  const int* tokpos = (const int*)d_in[1];
  const float* wqkv = (const float*)d_in[2];
  const float* wo = (const float*)d_in[3];
  float* out = (float*)d_out;

  char* ws = (char*)d_ws;
  u16* xb    = (u16*)(ws);
  u16* wqkvb = (u16*)(ws + ((size_t)8 << 20));
  u16* wob   = (u16*)(ws + ((size_t)14 << 20));
  u16* qb    = (u16*)(ws + ((size_t)16 << 20));
  u16* kb    = (u16*)(ws + ((size_t)24 << 20));
  u16* vbT   = (u16*)(ws + ((size_t)32 << 20));
  u16* attn  = (u16*)(ws + ((size_t)40 << 20));
  float2* cstab = (float2*)(ws + ((size_t)48 << 20));
  // split-K partials overlay xb/wqkvb (dead after gemm_qkv):
  u16* po    = (u16*)(ws);                        // 12.6MB
  float* pl  = (float*)(ws + ((size_t)13 << 20)); // 0.4MB

  prep_kernel<<<dim3(8704), dim3(256), 0, stream>>>(tokpos, cstab, x, wqkv, wo,
                                                    xb, wqkvb, wob);
  gemm_qkv_kernel<<<dim3(24, 32), dim3(256), 0, stream>>>(
      wqkvb, xb, qb, kb, vbT, cstab);
  flash_kernel<<<dim3(16, 96), dim3(256), 0, stream>>>(qb, kb, vbT, po, pl);
  reduce_kernel<<<dim3(16, 64), dim3(256), 0, stream>>>(po, pl, attn);
  gemm_out_kernel<<<dim3(32, 16), dim3(256), 0, stream>>>(attn, wob, out);
}

// Round 12
// 204.613 us; speedup vs baseline: 1.3343x; 1.0283x over previous
//
#include <hip/hip_runtime.h>
#include <stdint.h>

typedef unsigned short u16;
typedef __attribute__((ext_vector_type(8))) short bf16x8;
typedef __attribute__((ext_vector_type(4))) float f32x4;

#define LN_THETA 9.210340371976184f
#define SLEN 4096
#define DMODEL 1024

__device__ __forceinline__ u16 f2bf(float f) {
  union { float f; unsigned u; } v; v.f = f;
  unsigned u = v.u;
  return (u16)((u + 0x7FFFu + ((u >> 16) & 1u)) >> 16);
}
__device__ __forceinline__ float bf2f(u16 b) {
  union { unsigned u; float f; } v; v.u = ((unsigned)b) << 16;
  return v.f;
}
__device__ __forceinline__ float fexp2(float x) {
#if __has_builtin(__builtin_amdgcn_exp2f)
  return __builtin_amdgcn_exp2f(x);
#else
  return exp2f(x);
#endif
}
__device__ __forceinline__ unsigned pack_bf16_trunc(float lo, float hi) {
  union { float f; unsigned u; } a, b;
  a.f = hi; b.f = lo;
#if __has_builtin(__builtin_amdgcn_perm)
  return __builtin_amdgcn_perm(a.u, b.u, 0x07060302u);  // {hi16(a),hi16(b)}
#else
  return (a.u & 0xffff0000u) | (b.u >> 16);
#endif
}

__device__ __forceinline__ f32x4 mfma16(bf16x8 a, bf16x8 b, f32x4 c) {
  return __builtin_amdgcn_mfma_f32_16x16x32_bf16(a, b, c, 0, 0, 0);
}

__device__ __forceinline__ void async16(const u16* g, u16* l) {
  __builtin_amdgcn_global_load_lds(
      (const __attribute__((address_space(1))) unsigned int*)g,
      (__attribute__((address_space(3))) unsigned int*)l, 16, 0, 0);
}

// ---- prep: RoPE table (blocks 0..511) + fp32->bf16 converts (rest)
__global__ void prep_kernel(const int* __restrict__ tokpos,
                            float2* __restrict__ tab,
                            const float* __restrict__ x,
                            const float* __restrict__ wqkv,
                            const float* __restrict__ wo,
                            u16* __restrict__ xb, u16* __restrict__ wqkvb,
                            u16* __restrict__ wob) {
  if (blockIdx.x < 512) {
    int t = blockIdx.x * 256 + threadIdx.x;   // 0 .. 4096*32-1
    int s = t >> 5, i = t & 31;
    float inv = expf(-(float)(2 * i) * (LN_THETA / 64.0f));
    float ang = (float)tokpos[s] * inv;
    float sn, cs;
    sincosf(ang, &sn, &cs);
    tab[t] = make_float2(cs, sn);
    return;
  }
  int i = (blockIdx.x - 512) * 256 + threadIdx.x;   // float4 index
  const float* src;
  u16* dst;
  if (i < (1 << 20)) {
    src = x; dst = xb;
  } else if (i < (1 << 20) + (3 << 18)) {
    i -= (1 << 20); src = wqkv; dst = wqkvb;
  } else {
    i -= (1 << 20) + (3 << 18); src = wo; dst = wob;
  }
  float4 v = ((const float4*)src)[i];
  ushort4 o;
  o.x = f2bf(v.x); o.y = f2bf(v.y); o.z = f2bf(v.z); o.w = f2bf(v.w);
  ((ushort4*)dst)[i] = o;
}

// ---- 128x64 bf16 MFMA GEMM, qkv^T: D = Wqkv . x^T. BK=64, XOR-8 swizzle.
// grid (24 e-tiles, 64 s-tiles) = 1536 blocks = 6/CU for drain hiding.
// Fused RoPE; q pre-scaled by 0.125*log2(e) so flash uses raw exp2.
__global__ __launch_bounds__(256) void gemm_qkv_kernel(
    const u16* __restrict__ A, const u16* __restrict__ B,
    u16* __restrict__ qb, u16* __restrict__ kb,
    u16* __restrict__ vbT, const float2* __restrict__ cstab) {
  const int K = 1024;
  __shared__ __align__(16) char smem[24576];
  u16 (*As)[64] = (u16(*)[64])smem;            // 128x64 = 16KB
  u16 (*Bs)[64] = (u16(*)[64])(smem + 16384);  // 64x64 = 8KB
  u16 (*Ts)[136] = (u16(*)[136])smem;          // q/k epilogue 64x136 (17KB)
  u16 (*Tv)[72]  = (u16(*)[72])smem;           // v epilogue 128x72 (18KB)
  const int tid = threadIdx.x;
  const int wave = tid >> 6, lane = tid & 63;
  const int quad = lane >> 4, col = lane & 15;
  const int rowBase = blockIdx.x * 128;   // e
  const int colBase = blockIdx.y * 64;    // s
  const int wm = wave * 32;

  const int sr8 = lane >> 3;
  const int sseg = ((lane & 7) ^ sr8) * 8;
  const u16* gA = A + (size_t)(rowBase + wave * 8 + sr8) * K + sseg;
  const u16* gB = B + (size_t)(colBase + wave * 8 + sr8) * K + sseg;
  u16* ldsA = &As[wave * 8 + sr8][(lane & 7) * 8];
  u16* ldsB = &Bs[wave * 8 + sr8][(lane & 7) * 8];

  const int segh[2] = {((quad ^ (col & 7)) * 8), (((4 + quad) ^ (col & 7)) * 8)};

  f32x4 acc[2][4];
#pragma unroll
  for (int i = 0; i < 2; ++i)
#pragma unroll
    for (int j = 0; j < 4; ++j)
      acc[i][j] = f32x4{0.f, 0.f, 0.f, 0.f};

  for (int kk = 0; kk < K; kk += 64) {
    __syncthreads();
#pragma unroll
    for (int t = 0; t < 4; ++t)
      async16(gA + (size_t)t * 32 * K + kk, ldsA + t * 32 * 64);
#pragma unroll
    for (int t = 0; t < 2; ++t)
      async16(gB + (size_t)t * 32 * K + kk, ldsB + t * 32 * 64);
    __syncthreads();
#pragma unroll
    for (int h = 0; h < 2; ++h) {
      bf16x8 af[2], bfr[4];
#pragma unroll
      for (int i = 0; i < 2; ++i)
        af[i] = *(const bf16x8*)&As[wm + i * 16 + col][segh[h]];
#pragma unroll
      for (int j = 0; j < 4; ++j)
        bfr[j] = *(const bf16x8*)&Bs[j * 16 + col][segh[h]];
#pragma unroll
      for (int i = 0; i < 2; ++i)
#pragma unroll
        for (int j = 0; j < 4; ++j)
          acc[i][j] = mfma16(af[i], bfr[j], acc[i][j]);
    }
  }
  __syncthreads();   // all As/Bs reads done before Ts/Tv overwrite them

  const int sec = rowBase >> 10;   // block-uniform: 0=q 1=k 2=v

  if (sec < 2) {
    const float qs = (sec == 0) ? 0.125f * 1.4426950408889634f : 1.0f;
#pragma unroll
    for (int j = 0; j < 4; ++j) {
      int sl = j * 16 + col;
      int s = colBase + sl;
#pragma unroll
      for (int i = 0; i < 2; ++i) {
        int el = wm + i * 16 + quad * 4;
        int d = (rowBase + el) & 63;           // d % 4 == 0
        float v0 = acc[i][j][0], v1 = acc[i][j][1];
        float v2 = acc[i][j][2], v3 = acc[i][j][3];
        float2 cs0 = cstab[s * 32 + (d >> 1)];
        float2 cs1 = cstab[s * 32 + (d >> 1) + 1];
        ushort4 pk;
        pk.x = f2bf(qs * (v0 * cs0.x - v1 * cs0.y));
        pk.y = f2bf(qs * (v1 * cs0.x + v0 * cs0.y));
        pk.z = f2bf(qs * (v2 * cs1.x - v3 * cs1.y));
        pk.w = f2bf(qs * (v3 * cs1.x + v2 * cs1.y));
        *(ushort4*)&Ts[sl][el] = pk;           // 8B aligned
      }
    }
    __syncthreads();
    int sl = tid >> 2, ec = tid & 3;
    int hh = ((rowBase & 1023) >> 6) + (ec >> 1);
    int d0 = (ec & 1) * 32;
    u16* dst = (sec == 0 ? qb : kb) +
               ((size_t)hh * SLEN + colBase + sl) * 64 + d0;
    const u16* srcp = &Ts[sl][ec * 32];
#pragma unroll
    for (int kq = 0; kq < 4; ++kq)
      ((int4*)dst)[kq] = ((const int4*)srcp)[kq];
  } else {
#pragma unroll
    for (int j = 0; j < 4; ++j) {
      int sl = j * 16 + col;
#pragma unroll
      for (int i = 0; i < 2; ++i) {
        int el = wm + i * 16 + quad * 4;
#pragma unroll
        for (int r = 0; r < 4; ++r)
          Tv[el + r][sl] = f2bf(acc[i][j][r]);
      }
    }
    __syncthreads();
    int el = tid >> 1, sc = tid & 1;
    int e = rowBase - 2048 + el;
    int hh = e >> 6, d = e & 63;
    u16* dst = vbT + (size_t)(hh * 64 + d) * SLEN + colBase + sc * 32;
    const u16* srcp = &Tv[el][sc * 32];
#pragma unroll
    for (int kq = 0; kq < 4; ++kq)
      ((int4*)dst)[kq] = ((const int4*)srcp)[kq];
  }
}

// ---- 64x64 bf16 MFMA GEMM, out = attn(4096xK) . Wo(1024xK)^T, BK=64.
// grid (64,16) = 1024 blocks = 4/CU.
__global__ __launch_bounds__(256) void gemm_out_kernel(
    const u16* __restrict__ A, const u16* __restrict__ B,
    float* __restrict__ outf) {
  const int K = 1024;
  __shared__ __align__(16) u16 As[64][64];
  __shared__ __align__(16) u16 Bs[64][64];
  const int tid = threadIdx.x;
  const int wave = tid >> 6, lane = tid & 63;
  const int quad = lane >> 4, col = lane & 15;
  const int rowBase = blockIdx.x * 64;
  const int colBase = blockIdx.y * 64;

  const int sr8 = lane >> 3;
  const int sseg = ((lane & 7) ^ sr8) * 8;
  const u16* gA = A + (size_t)(rowBase + wave * 8 + sr8) * K + sseg;
  const u16* gB = B + (size_t)(colBase + wave * 8 + sr8) * K + sseg;
  u16* ldsA = &As[wave * 8 + sr8][(lane & 7) * 8];
  u16* ldsB = &Bs[wave * 8 + sr8][(lane & 7) * 8];

  const int segh[2] = {((quad ^ (col & 7)) * 8), (((4 + quad) ^ (col & 7)) * 8)};

  f32x4 acc[4];
#pragma unroll
  for (int j = 0; j < 4; ++j) acc[j] = f32x4{0.f, 0.f, 0.f, 0.f};

  for (int kk = 0; kk < K; kk += 64) {
    __syncthreads();
#pragma unroll
    for (int t = 0; t < 2; ++t) {
      async16(gA + (size_t)t * 32 * K + kk, ldsA + t * 32 * 64);
      async16(gB + (size_t)t * 32 * K + kk, ldsB + t * 32 * 64);
    }
    __syncthreads();
#pragma unroll
    for (int h = 0; h < 2; ++h) {
      bf16x8 af = *(const bf16x8*)&As[wave * 16 + col][segh[h]];
      bf16x8 bfr[4];
#pragma unroll
      for (int j = 0; j < 4; ++j)
        bfr[j] = *(const bf16x8*)&Bs[j * 16 + col][segh[h]];
#pragma unroll
      for (int j = 0; j < 4; ++j)
        acc[j] = mfma16(af, bfr[j], acc[j]);
    }
  }

  int r0 = rowBase + wave * 16 + quad * 4;
#pragma unroll
  for (int j = 0; j < 4; ++j) {
    int cc = colBase + j * 16 + col;
#pragma unroll
    for (int r = 0; r < 4; ++r)
      outf[(size_t)(r0 + r) * DMODEL + cc] = acc[j][r];
  }
}

// ---- causal flash attention v12: split-K items, 4 waves/block, 1 strip/wave.
// NEW: compute S^T = K.Q^T (swap MFMA operands; kf/qf fragment reads are
// layout-identical). Lane then holds P[key=16jb+4quad+r][q=col]: consecutive
// r = consecutive keys -> pack pairs to b32 and write Pld with 8 ds_write_b32
// (was 16 trunc + 16 ds_write_b16). Pld semantic layout [q][key] unchanged,
// so the b128 A-fragment read side is identical.
__global__ __launch_bounds__(256) void flash_kernel(
    const u16* __restrict__ qbuf, const u16* __restrict__ kbuf,
    const u16* __restrict__ vbT, u16* __restrict__ po,
    float* __restrict__ pl) {
  const int S = SLEN;
  const int h = blockIdx.x;
  const int y = blockIdx.y;
  int tile, c0, c1;
  if (y < 32) {                       // tiles 32..63, segment 0 (32 chunks)
    tile = 32 + y; c0 = 0; c1 = 31;
  } else {
    int k = (y - 32) >> 1;
    if ((y - 32) & 1) { tile = 31 - k; c0 = 0; c1 = tile; }   // 1-seg tiles
    else { tile = 63 - k; c0 = 32; c1 = tile; }               // segment 1
  }
  const int id = (tile < 32) ? tile : (32 + 2 * (tile - 32) + (c0 ? 1 : 0));

  const int wave = threadIdx.x >> 6, lane = threadIdx.x & 63;
  const int quad = lane >> 4, col = lane & 15;
  const u16* Q = qbuf + (size_t)h * S * 64;
  const u16* Kh = kbuf + (size_t)h * S * 64;
  const u16* Vt = vbT + (size_t)h * 64 * S;

  __shared__ __align__(16) u16 Ks[64][64];
  __shared__ __align__(16) u16 Vs[64][64];
  __shared__ __align__(16) u16 Pld[4][16][72];   // [wave][q][key(+8 pad)]

  const int sr = lane >> 3;
  const int sw = ((lane & 7) ^ sr) * 8;
  const int dcol = (lane & 7) * 8;
  const int segA = ((quad ^ (col & 7)) * 8);
  const int segB = (((quad ^ 4) ^ (col & 7)) * 8);

  const int qrow0 = tile * 64 + wave * 16;
  const int wcol = wave * 16 + col;   // q row rel. to tile*64 (mask rhs)

  bf16x8 qf0, qf1;
  {
    const u16* qp = &Q[(size_t)(qrow0 + col) * 64 + quad * 8];
    qf0 = *(const bf16x8*)qp;
    qf1 = *(const bf16x8*)(qp + 32);
  }

  const bf16x8 ones = {(short)0x3F80, (short)0x3F80, (short)0x3F80,
                       (short)0x3F80, (short)0x3F80, (short)0x3F80,
                       (short)0x3F80, (short)0x3F80};

  f32x4 o[4], lacc;
#pragma unroll
  for (int n = 0; n < 4; ++n) o[n] = f32x4{0.f, 0.f, 0.f, 0.f};
  lacc = f32x4{0.f, 0.f, 0.f, 0.f};

  for (int c = c0; c <= c1; ++c) {
    const int k0 = c * 64;
    __syncthreads();        // previous chunk's readers done
    {
#pragma unroll
      for (int t = 0; t < 2; ++t) {
        int row = wave * 16 + t * 8 + sr;
        async16(Kh + (size_t)(k0 + row) * 64 + sw, &Ks[row][dcol]);
        async16(Vt + (size_t)row * S + k0 + sw, &Vs[row][dcol]);
      }
    }
    __syncthreads();        // stage drained

    bf16x8 kf0[4], kf1[4], vf0[4], vf1[4];
#pragma unroll
    for (int j = 0; j < 4; ++j) {
      kf0[j] = *(const bf16x8*)&Ks[16 * j + col][segA];
      kf1[j] = *(const bf16x8*)&Ks[16 * j + col][segB];
    }
#pragma unroll
    for (int n = 0; n < 4; ++n) {
      vf0[n] = *(const bf16x8*)&Vs[16 * n + col][segA];
      vf1[n] = *(const bf16x8*)&Vs[16 * n + col][segB];
    }
    const bool lastc = (c == tile);   // diagonal chunk
    // S^T = K.Q^T: A=kf (m=key), B=qf (n=q) -> C row=key_local, col=q
    f32x4 st[4];
#pragma unroll
    for (int jb = 0; jb < 4; ++jb)
      st[jb] = mfma16(kf1[jb], qf1,
                      mfma16(kf0[jb], qf0, f32x4{0.f, 0.f, 0.f, 0.f}));
    float p[4][4];
#pragma unroll
    for (int jb = 0; jb < 4; ++jb)
#pragma unroll
      for (int r = 0; r < 4; ++r) {
        float e = fexp2(st[jb][r]);   // scale & log2e pre-folded into q
        if (lastc && (16 * jb + quad * 4 + r > wcol)) e = 0.f;  // key>q
        p[jb][r] = e;
      }
    // pack consecutive-key pairs, write b32s into Pld[wave][q=col][key]
#pragma unroll
    for (int jb = 0; jb < 4; ++jb)
#pragma unroll
      for (int u = 0; u < 2; ++u) {
        unsigned pk = pack_bf16_trunc(p[jb][2 * u], p[jb][2 * u + 1]);
        *(unsigned*)&Pld[wave][col][16 * jb + quad * 4 + 2 * u] = pk;
      }
    bf16x8 pa0 = *(const bf16x8*)&Pld[wave][col][quad * 8];
    bf16x8 pa1 = *(const bf16x8*)&Pld[wave][col][quad * 8 + 32];
    lacc = mfma16(pa1, ones, mfma16(pa0, ones, lacc));
#pragma unroll
    for (int n = 0; n < 4; ++n)
      o[n] = mfma16(pa1, vf1[n], mfma16(pa0, vf0[n], o[n]));
  }

  // epilogue: write UNNORMALIZED partial o (bf16) and partial l (fp32)
  u16* pob = po + (((size_t)h * 96 + id) * 64) * 64;
  float* plb = pl + ((size_t)h * 96 + id) * 64;
#pragma unroll
  for (int r = 0; r < 4; ++r) {
    int rowl = wave * 16 + quad * 4 + r;
    u16* dst = pob + (size_t)rowl * 64 + col;
#pragma unroll
    for (int n = 0; n < 4; ++n) dst[16 * n] = f2bf(o[n][r]);
    if (col == 0) plb[rowl] = lacc[r];
  }
}

// ---- combine split-K partials: attn[row][h*64+dim] = sum(po)/sum(pl)
__global__ __launch_bounds__(256) void reduce_kernel(
    const u16* __restrict__ po, const float* __restrict__ pl,
    u16* __restrict__ attn) {
  const int h = blockIdx.x, tile = blockIdx.y;
  const int tid = threadIdx.x;
  const int row = tid >> 2, dg = (tid & 3) * 16;
  int id0, ns;
  if (tile < 32) { id0 = tile; ns = 1; }
  else { id0 = 32 + 2 * (tile - 32); ns = 2; }

  float acc[16];
#pragma unroll
  for (int q = 0; q < 16; ++q) acc[q] = 0.f;
  float l = 0.f;
  for (int s = 0; s < ns; ++s) {
    const size_t base = ((size_t)h * 96 + id0 + s) * 64;
    const u16* p = po + (base + row) * 64 + dg;
    l += pl[base + row];
#pragma unroll
    for (int q = 0; q < 16; ++q) acc[q] += bf2f(p[q]);
  }
  float inv = 1.0f / l;
  u16* dst = attn + (size_t)(tile * 64 + row) * DMODEL + h * 64 + dg;
  ushort4 o0, o1, o2, o3;
  o0.x = f2bf(acc[0] * inv);  o0.y = f2bf(acc[1] * inv);
  o0.z = f2bf(acc[2] * inv);  o0.w = f2bf(acc[3] * inv);
  o1.x = f2bf(acc[4] * inv);  o1.y = f2bf(acc[5] * inv);
  o1.z = f2bf(acc[6] * inv);  o1.w = f2bf(acc[7] * inv);
  o2.x = f2bf(acc[8] * inv);  o2.y = f2bf(acc[9] * inv);
  o2.z = f2bf(acc[10] * inv); o2.w = f2bf(acc[11] * inv);
  o3.x = f2bf(acc[12] * inv); o3.y = f2bf(acc[13] * inv);
  o3.z = f2bf(acc[14] * inv); o3.w = f2bf(acc[15] * inv);
  ((ushort4*)dst)[0] = o0; ((ushort4*)dst)[1] = o1;
  ((ushort4*)dst)[2] = o2; ((ushort4*)dst)[3] = o3;
}

extern "C" void kernel_launch(void* const* d_in, const int* in_sizes, int n_in,
                              void* d_out, int out_size, void* d_ws,
                              size_t ws_size, hipStream_t stream) {
  const float* x = (const float*)d_in[0];
  const int* tokpos = (const int*)d_in[1];
  const float* wqkv = (const float*)d_in[2];
  const float* wo = (const float*)d_in[3];
  float* out = (float*)d_out;

  char* ws = (char*)d_ws;
  u16* xb    = (u16*)(ws);
  u16* wqkvb = (u16*)(ws + ((size_t)8 << 20));
  u16* wob   = (u16*)(ws + ((size_t)14 << 20));
  u16* qb    = (u16*)(ws + ((size_t)16 << 20));
  u16* kb    = (u16*)(ws + ((size_t)24 << 20));
  u16* vbT   = (u16*)(ws + ((size_t)32 << 20));
  u16* attn  = (u16*)(ws + ((size_t)40 << 20));
  float2* cstab = (float2*)(ws + ((size_t)48 << 20));
  // split-K partials overlay xb/wqkvb (dead after gemm_qkv):
  u16* po    = (u16*)(ws);                        // 12.6MB
  float* pl  = (float*)(ws + ((size_t)13 << 20)); // 0.4MB

  prep_kernel<<<dim3(8704), dim3(256), 0, stream>>>(tokpos, cstab, x, wqkv, wo,
                                                    xb, wqkvb, wob);
  gemm_qkv_kernel<<<dim3(24, 64), dim3(256), 0, stream>>>(
      wqkvb, xb, qb, kb, vbT, cstab);
  flash_kernel<<<dim3(16, 96), dim3(256), 0, stream>>>(qb, kb, vbT, po, pl);
  reduce_kernel<<<dim3(16, 64), dim3(256), 0, stream>>>(po, pl, attn);
  gemm_out_kernel<<<dim3(64, 16), dim3(256), 0, stream>>>(attn, wob, out);
}